// Round 7
// baseline (436.576 us; speedup 1.0000x reference)
//
#include <hip/hip_runtime.h>

#define NSLOPE 0.2f

typedef __bf16 bf16x8 __attribute__((ext_vector_type(8)));
typedef __bf16 bf16x4 __attribute__((ext_vector_type(4)));
typedef float  f32x4  __attribute__((ext_vector_type(4)));

// ======================= CSR build (per-launch; ws is re-poisoned) ==========
__global__ void init_cnt_kernel(int* cnt, int n){
  int i = blockIdx.x*blockDim.x + threadIdx.x;
  if (i < n) cnt[i] = 1;                       // count the self-loop up front
}

__global__ void hist_kernel(const int* __restrict__ ei, int E, int* cnt){
  int e = blockIdx.x*blockDim.x + threadIdx.x;
  if (e < E) atomicAdd(&cnt[ei[E + e]], 1);    // dst row of edge_index
}

// single-block scan, wave-shuffle based (4 barriers per 1024-chunk)
__global__ void scan_kernel(const int* __restrict__ cnt, int* __restrict__ rowptr,
                            int* __restrict__ cursor, int n){
  __shared__ int wsum[16];
  __shared__ int carry, chunk_total;
  int t = threadIdx.x, lane = t & 63, wid = t >> 6;
  if (t == 0) carry = 0;
  __syncthreads();
  for (int base = 0; base < n; base += 1024){
    int idx = base + t;
    int v = (idx < n) ? cnt[idx] : 0;
    int inc = v;
#pragma unroll
    for (int off = 1; off < 64; off <<= 1){
      int u = __shfl_up(inc, off);
      if (lane >= off) inc += u;
    }
    if (lane == 63) wsum[wid] = inc;
    __syncthreads();
    if (t == 0){
      int s = 0;
#pragma unroll
      for (int i = 0; i < 16; i++){ int x = wsum[i]; wsum[i] = s; s += x; }
      chunk_total = s;
    }
    __syncthreads();
    int excl = carry + wsum[wid] + inc - v;
    if (idx < n){ rowptr[idx] = excl; cursor[idx] = excl; }
    __syncthreads();
    if (t == 0) carry += chunk_total;
    __syncthreads();
  }
  if (t == 0) rowptr[n] = carry;
}

__global__ void fill_kernel(const int* __restrict__ ei, int E, int n,
                            int* cursor, int* __restrict__ col){
  int i = blockIdx.x*blockDim.x + threadIdx.x;
  if (i < E){
    int s = ei[i], d = ei[E + i];
    int slot = atomicAdd(&cursor[d], 1);
    col[slot] = s;
  } else if (i < E + n){
    int v = i - E;                             // self loop (v -> v)
    int slot = atomicAdd(&cursor[v], 1);
    col[slot] = v;
  }
}

// ============ W [K][Nc] fp32 -> Bt_hi/Bt_lo [Nc][K] bf16 (split) ============
__global__ __launch_bounds__(256) void wsplit_kernel(
    const float* __restrict__ W, __bf16* __restrict__ Bthi,
    __bf16* __restrict__ Btlo, int K, int Nc){
  __shared__ float hi_s[32][33], lo_s[32][33];
  int tx = threadIdx.x & 31, ty = threadIdx.x >> 5;   // 32 x 8
  int k0 = blockIdx.x * 32, n0 = blockIdx.y * 32;
#pragma unroll
  for (int i = 0; i < 4; i++){
    int r = ty + i*8;
    float v = W[(size_t)(k0 + r)*Nc + n0 + tx];
    float h = (float)(__bf16)v;
    hi_s[r][tx] = h;
    lo_s[r][tx] = v - h;
  }
  __syncthreads();
#pragma unroll
  for (int i = 0; i < 4; i++){
    int n = ty + i*8;
    Bthi[(size_t)(n0 + n)*K + k0 + tx] = (__bf16)hi_s[tx][n];
    Btlo[(size_t)(n0 + n)*K + k0 + tx] = (__bf16)lo_s[tx][n];
  }
}

// ============ x [N][K] fp32 -> hi/lo bf16 (row-major, same layout) ==========
__global__ __launch_bounds__(256) void split_kernel(
    const float* __restrict__ X, __bf16* __restrict__ Xhi,
    __bf16* __restrict__ Xlo, int total){
  int i = (blockIdx.x*256 + threadIdx.x)*4;
  if (i < total){
    float4 v = *(const float4*)(X + i);
    float f[4] = {v.x, v.y, v.z, v.w};
    bf16x4 h, l;
#pragma unroll
    for (int u = 0; u < 4; u++){
      __bf16 hh = (__bf16)f[u];
      h[u] = hh;
      l[u] = (__bf16)(f[u] - (float)hh);
    }
    *(bf16x4*)(Xhi + i) = h;
    *(bf16x4*)(Xlo + i) = l;
  }
}

// ========== split-bf16 MFMA GEMM, pre-split A and B =========================
// C = Ahi*Bhi + Ahi*Blo + Alo*Bhi.  64x64 tile, 128 thr = 2 waves, BK=32.
// LDS chunk layout (16B chunks): chunk c <-> row=(c>>6)*16+(c&15), kchunk=(c>>4)&3.
//   Staging: thread t WRITES chunks t and t+128 at addr t*16 -> conflict-free.
//   Fragment reads: lane(q,mm) reads chunk i*64 + q*16 + mm -> 256B/quarter-wave,
//   conflict-free. Double-buffered, one barrier per K-iter, register prefetch.
// Grid is 1-D (mblocks*8); XCD swizzle co-locates the 8 N-blocks of one
// A-stripe on one XCD so the A-stripe stays in that XCD's L2.
__global__ __launch_bounds__(128) void gemm_mfma(
    const __bf16* __restrict__ Ahi, const __bf16* __restrict__ Alo,
    const __bf16* __restrict__ Bthi, const __bf16* __restrict__ Btlo,
    float* __restrict__ C, int M, int Nc, int K){
  __shared__ uint4 lds[2][4][256];   // [buf][Ah,Al,Bh,Bl][chunk] = 32 KiB
  int t = threadIdx.x;

  // ---- XCD swizzle: h -> w so that w-consecutive (same A-stripe) share XCD
  int h = blockIdx.x;
  int per = gridDim.x >> 3;              // blocks per XCD
  int w_ = (h & 7) * per + (h >> 3);
  int bm = (w_ >> 3) * 64;               // Nc/64 == 8 always here
  int bn = (w_ & 7) * 64;

  int lane = t & 63, wv = t >> 6;
  int mm = lane & 15, q = lane >> 4;

  // staging decode: chunk t -> (rowA0, kc); chunk t+128 -> (rowA0+32, kc)
  const int rowA0 = ((t >> 6) << 4) | (t & 15);   // [0,32)
  const int rowA1 = rowA0 + 32;
  const int kc    = (t >> 4) & 3;

  f32x4 acc[4][2];
#pragma unroll
  for (int i = 0; i < 4; i++)
#pragma unroll
    for (int j = 0; j < 2; j++)
#pragma unroll
      for (int r = 0; r < 4; r++) acc[i][j][r] = 0.f;

  const uint4 zero4 = make_uint4(0,0,0,0);
  uint4 pAh0, pAh1, pAl0, pAl1, pBh0, pBh1, pBl0, pBl1;

  const bool ok0 = (bm + rowA0) < M, ok1 = (bm + rowA1) < M;
  const size_t a0off = (size_t)(bm + rowA0)*K + kc*8;
  const size_t a1off = (size_t)(bm + rowA1)*K + kc*8;
  const size_t b0off = (size_t)(bn + rowA0)*K + kc*8;
  const size_t b1off = (size_t)(bn + rowA1)*K + kc*8;

  // ---- prefetch tile 0 ----
  pAh0 = ok0 ? *(const uint4*)(Ahi + a0off) : zero4;
  pAh1 = ok1 ? *(const uint4*)(Ahi + a1off) : zero4;
  pAl0 = ok0 ? *(const uint4*)(Alo + a0off) : zero4;
  pAl1 = ok1 ? *(const uint4*)(Alo + a1off) : zero4;
  pBh0 = *(const uint4*)(Bthi + b0off);
  pBh1 = *(const uint4*)(Bthi + b1off);
  pBl0 = *(const uint4*)(Btlo + b0off);
  pBl1 = *(const uint4*)(Btlo + b1off);

  lds[0][0][t] = pAh0; lds[0][0][t+128] = pAh1;
  lds[0][1][t] = pAl0; lds[0][1][t+128] = pAl1;
  lds[0][2][t] = pBh0; lds[0][2][t+128] = pBh1;
  lds[0][3][t] = pBl0; lds[0][3][t+128] = pBl1;
  __syncthreads();

  const int niter = K >> 5;
  int b = 0;
  const int fa = q*16 + mm;
  for (int it = 0; it < niter; it++){
    if (it + 1 < niter){
      int k0 = (it + 1) << 5;
      pAh0 = ok0 ? *(const uint4*)(Ahi + a0off + k0) : zero4;
      pAh1 = ok1 ? *(const uint4*)(Ahi + a1off + k0) : zero4;
      pAl0 = ok0 ? *(const uint4*)(Alo + a0off + k0) : zero4;
      pAl1 = ok1 ? *(const uint4*)(Alo + a1off + k0) : zero4;
      pBh0 = *(const uint4*)(Bthi + b0off + k0);
      pBh1 = *(const uint4*)(Bthi + b1off + k0);
      pBl0 = *(const uint4*)(Btlo + b0off + k0);
      pBl1 = *(const uint4*)(Btlo + b1off + k0);
    }
    // ---- fragments from lds[b] ----
    bf16x8 a_h[4], a_l[4], b_h[2], b_l[2];
#pragma unroll
    for (int i = 0; i < 4; i++){
      a_h[i] = *(bf16x8*)&lds[b][0][i*64 + fa];
      a_l[i] = *(bf16x8*)&lds[b][1][i*64 + fa];
    }
#pragma unroll
    for (int jj = 0; jj < 2; jj++){
      b_h[jj] = *(bf16x8*)&lds[b][2][(wv*2 + jj)*64 + fa];
      b_l[jj] = *(bf16x8*)&lds[b][3][(wv*2 + jj)*64 + fa];
    }
#pragma unroll
    for (int i = 0; i < 4; i++)
#pragma unroll
      for (int jj = 0; jj < 2; jj++){
        acc[i][jj] = __builtin_amdgcn_mfma_f32_16x16x32_bf16(a_h[i], b_h[jj], acc[i][jj], 0, 0, 0);
        acc[i][jj] = __builtin_amdgcn_mfma_f32_16x16x32_bf16(a_h[i], b_l[jj], acc[i][jj], 0, 0, 0);
        acc[i][jj] = __builtin_amdgcn_mfma_f32_16x16x32_bf16(a_l[i], b_h[jj], acc[i][jj], 0, 0, 0);
      }
    if (it + 1 < niter){
      int nb = b ^ 1;
      lds[nb][0][t] = pAh0; lds[nb][0][t+128] = pAh1;
      lds[nb][1][t] = pAl0; lds[nb][1][t+128] = pAl1;
      lds[nb][2][t] = pBh0; lds[nb][2][t+128] = pBh1;
      lds[nb][3][t] = pBl0; lds[nb][3][t+128] = pBl1;
    }
    __syncthreads();
    b ^= 1;
  }

  // ---- store: reg r -> row = q*4 + r, col = mm ----
#pragma unroll
  for (int i = 0; i < 4; i++){
#pragma unroll
    for (int jj = 0; jj < 2; jj++){
      int colc = bn + wv*32 + jj*16 + mm;
#pragma unroll
      for (int r = 0; r < 4; r++){
        int row = bm + i*16 + q*4 + r;
        if (row < M) C[(size_t)row*Nc + colc] = acc[i][jj][r];
      }
    }
  }
}

// ===== attention coefficients + bf16 copy of H for the gather ==============
template<int H, int CH>
__global__ __launch_bounds__(128) void attn_coef_kernel(
    const float* __restrict__ Hm, const float* __restrict__ asrc,
    const float* __restrict__ adst, float* __restrict__ al_s,
    float* __restrict__ al_d, __bf16* __restrict__ Hb){
  int b = blockIdx.x;                 // n*H + h
  int n = b / H, h = b % H;
  const float* row = Hm + (size_t)n*(H*CH) + (size_t)h*CH;
  int t = threadIdx.x;
  float ss = 0.f, sd = 0.f;
  for (int c = t; c < CH; c += 128){
    float v = row[c];
    Hb[(size_t)b*CH + c] = (__bf16)v;   // same flat layout as Hm
    ss += v * asrc[h*CH + c];
    sd += v * adst[h*CH + c];
  }
#pragma unroll
  for (int off = 32; off > 0; off >>= 1){
    ss += __shfl_down(ss, off);
    sd += __shfl_down(sd, off);
  }
  __shared__ float r0[2], r1[2];
  int wave = t >> 6, lane = t & 63;
  if (lane == 0){ r0[wave] = ss; r1[wave] = sd; }
  __syncthreads();
  if (t == 0){ al_s[b] = r0[0] + r0[1]; al_d[b] = r1[0] + r1[1]; }
}

// ========== per-dst softmax: one WAVE per node, shuffle-only ================
template<int H>
__global__ __launch_bounds__(64) void alpha_kernel(
    const float* __restrict__ al_s, const float* __restrict__ al_d,
    const int* __restrict__ rowptr, const int* __restrict__ col,
    float* __restrict__ alphaE, float* __restrict__ denom){
  int d = blockIdx.x;
  int lane = threadIdx.x;              // 0..63
  int start = rowptr[d], end = rowptr[d + 1];

  float ald[H];
#pragma unroll
  for (int h = 0; h < H; h++) ald[h] = al_d[(size_t)d*H + h];

  float mx[H];
#pragma unroll
  for (int h = 0; h < H; h++) mx[h] = -1e30f;
  for (int e = start + lane; e < end; e += 64){
    int s = col[e];
#pragma unroll
    for (int h = 0; h < H; h++){
      float v = al_s[(size_t)s*H + h] + ald[h];
      v = (v > 0.f) ? v : NSLOPE * v;
      mx[h] = fmaxf(mx[h], v);
    }
  }
#pragma unroll
  for (int h = 0; h < H; h++)
#pragma unroll
    for (int off = 32; off > 0; off >>= 1)
      mx[h] = fmaxf(mx[h], __shfl_xor(mx[h], off));

  float sm[H] = {};
  for (int e = start + lane; e < end; e += 64){
    int s = col[e];
#pragma unroll
    for (int h = 0; h < H; h++){
      float v = al_s[(size_t)s*H + h] + ald[h];
      v = (v > 0.f) ? v : NSLOPE * v;
      float ev = __expf(v - mx[h]);
      alphaE[(size_t)e*H + h] = ev;
      sm[h] += ev;
    }
  }
#pragma unroll
  for (int h = 0; h < H; h++)
#pragma unroll
    for (int off = 32; off > 0; off >>= 1)
      sm[h] += __shfl_xor(sm[h], off);
  if (lane == 0){
#pragma unroll
    for (int h = 0; h < H; h++) denom[(size_t)d*H + h] = sm[h];
  }
}

// ====== weighted gather from bf16 rows ======================================
// MODE 0: fp32 out, no ReLU (layer 3).  MODE 1: ReLU + bf16 hi/lo out.
template<int H, int MODE>
__global__ __launch_bounds__(128) void aggregate_kernel(
    const __bf16* __restrict__ Hb, const float* __restrict__ alphaE,
    const float* __restrict__ denom, const int* __restrict__ rowptr,
    const int* __restrict__ col, const float* __restrict__ bias,
    float* __restrict__ outF, __bf16* __restrict__ fhi,
    __bf16* __restrict__ flo){
  __shared__ int   src_lds[64];
  __shared__ float a_lds[64 * H];
  __shared__ float part[512];

  int d = blockIdx.x;
  int t = threadIdx.x;
  int g = t >> 6, lane = t & 63;
  int start = rowptr[d], end = rowptr[d + 1];
  const int hh = (lane * H) >> 6;              // head of lane's 8 channels
  const bf16x8* __restrict__ Hb8 = (const bf16x8*)Hb;   // row stride = 64

  float a0[8] = {};
  float a1[8] = {};
  for (int c0 = start; c0 < end; c0 += 64){
    int cnt = min(64, end - c0);
    if (t < cnt){
      src_lds[t] = col[c0 + t];
#pragma unroll
      for (int h = 0; h < H; h++)
        a_lds[t*H + h] = alphaE[(size_t)(c0 + t)*H + h];
    }
    __syncthreads();
    int i = g;
    for (; i + 2 < cnt; i += 4){
      int s0 = src_lds[i], s1 = src_lds[i + 2];
      float e0 = a_lds[i*H + hh], e1 = a_lds[(i + 2)*H + hh];
      bf16x8 v0 = Hb8[(size_t)s0*64 + lane];
      bf16x8 v1 = Hb8[(size_t)s1*64 + lane];
#pragma unroll
      for (int u = 0; u < 8; u++){
        a0[u] += e0 * (float)v0[u];
        a1[u] += e1 * (float)v1[u];
      }
    }
    for (; i < cnt; i += 2){
      int s0 = src_lds[i];
      float e0 = a_lds[i*H + hh];
      bf16x8 v0 = Hb8[(size_t)s0*64 + lane];
#pragma unroll
      for (int u = 0; u < 8; u++) a0[u] += e0 * (float)v0[u];
    }
    __syncthreads();
  }

  if (g == 1){
#pragma unroll
    for (int u = 0; u < 8; u++) part[lane*8 + u] = a0[u] + a1[u];
  }
  __syncthreads();
  if (g == 0){
    float inv = 1.f / denom[(size_t)d*H + hh];
    float r[8];
#pragma unroll
    for (int u = 0; u < 8; u++){
      float v = (a0[u] + a1[u] + part[lane*8 + u]) * inv + bias[lane*8 + u];
      if (MODE == 1) v = fmaxf(v, 0.f);
      r[u] = v;
    }
    if (MODE == 1){
      bf16x8 hv, lv;
#pragma unroll
      for (int u = 0; u < 8; u++){
        __bf16 h = (__bf16)r[u];
        hv[u] = h;
        lv[u] = (__bf16)(r[u] - (float)h);
      }
      *(bf16x8*)(fhi + (size_t)d*512 + lane*8) = hv;
      *(bf16x8*)(flo + (size_t)d*512 + lane*8) = lv;
    } else {
      float4* op = (float4*)(outF + (size_t)d*512 + lane*8);
      op[0] = make_float4(r[0], r[1], r[2], r[3]);
      op[1] = make_float4(r[4], r[5], r[6], r[7]);
    }
  }
}

// =========================== launch =========================================
extern "C" void kernel_launch(void* const* d_in, const int* in_sizes, int n_in,
                              void* d_out, int out_size, void* d_ws, size_t ws_size,
                              hipStream_t stream){
  const float* x   = (const float*)d_in[0];
  const int*   ei  = (const int*)  d_in[1];
  const float* W1  = (const float*)d_in[2];
  const float* as1 = (const float*)d_in[3];
  const float* ad1 = (const float*)d_in[4];
  const float* b1  = (const float*)d_in[5];
  const float* W2  = (const float*)d_in[6];
  const float* as2 = (const float*)d_in[7];
  const float* ad2 = (const float*)d_in[8];
  const float* b2  = (const float*)d_in[9];
  const float* W3  = (const float*)d_in[10];
  const float* as3 = (const float*)d_in[11];
  const float* ad3 = (const float*)d_in[12];
  const float* b3  = (const float*)d_in[13];
  float* out = (float*)d_out;

  const int N = in_sizes[0] / 128;   // 10000
  const int E = in_sizes[1] / 2;     // 320000
  const int F = 512;
  const int Etot = E + N;

  // workspace carve-up (same footprint as R5)
  float*  Hmat   = (float*)d_ws;                      // N*512 fp32
  __bf16* feat_hi= (__bf16*)(Hmat + (size_t)N*F);     // N*512 bf16
  __bf16* feat_lo= feat_hi + (size_t)N*F;             // N*512 bf16
  float*  al_s   = (float*)(feat_lo + (size_t)N*F);   // N*4
  float*  al_d   = al_s + (size_t)N*4;                // N*4
  float*  alphaE = al_d + (size_t)N*4;                // (E+N)*4
  float*  denom  = alphaE + (size_t)Etot*4;           // N*4
  int*    cnt    = (int*)(denom + (size_t)N*4);       // N
  int*    rowptr = cnt + N;                           // N+1
  int*    cursor = rowptr + N + 1;                    // N
  int*    col    = cursor + N;                        // E+N
  uintptr_t p  = (uintptr_t)(col + Etot);
  p = (p + 15) & ~(uintptr_t)15;
  __bf16* Bth = (__bf16*)p;                           // 512*512 bf16
  __bf16* Btl = Bth + 512*512;                        // 512*512 bf16
  __bf16* Hb  = Btl + 512*512;                        // N*512 bf16 (gather)
  // x hi/lo aliases alphaE region; consumed before alpha_kernel writes it.
  __bf16* Xhi = (__bf16*)alphaE;
  __bf16* Xlo = Xhi + (size_t)N*128;

  // CSR by destination
  init_cnt_kernel<<<(N+255)/256, 256, 0, stream>>>(cnt, N);
  hist_kernel<<<(E+255)/256, 256, 0, stream>>>(ei, E, cnt);
  scan_kernel<<<1, 1024, 0, stream>>>(cnt, rowptr, cursor, N);
  fill_kernel<<<(E+N+255)/256, 256, 0, stream>>>(ei, E, N, cursor, col);

  const int mblocks = (N + 63)/64;          // 157
  const int ggrid = mblocks * (F/64);       // 1256, 1-D (XCD swizzle inside)

  // ---- layer 1: x[N,128] @ W1[128,512] ----
  split_kernel<<<(N*128/4 + 255)/256, 256, 0, stream>>>(x, Xhi, Xlo, N*128);
  wsplit_kernel<<<dim3(128/32, F/32), 256, 0, stream>>>(W1, Bth, Btl, 128, F);
  gemm_mfma<<<ggrid, 128, 0, stream>>>(Xhi, Xlo, Bth, Btl, Hmat, N, F, 128);
  attn_coef_kernel<4,128><<<N*4, 128, 0, stream>>>(Hmat, as1, ad1, al_s, al_d, Hb);
  alpha_kernel<4><<<N, 64, 0, stream>>>(al_s, al_d, rowptr, col, alphaE, denom);
  aggregate_kernel<4,1><<<N, 128, 0, stream>>>(Hb, alphaE, denom, rowptr, col, b1,
                                               (float*)nullptr, feat_hi, feat_lo);

  // ---- layer 2: feat[N,512] @ W2[512,512] ----
  wsplit_kernel<<<dim3(F/32, F/32), 256, 0, stream>>>(W2, Bth, Btl, F, F);
  gemm_mfma<<<ggrid, 128, 0, stream>>>(feat_hi, feat_lo, Bth, Btl, Hmat, N, F, F);
  attn_coef_kernel<4,128><<<N*4, 128, 0, stream>>>(Hmat, as2, ad2, al_s, al_d, Hb);
  alpha_kernel<4><<<N, 64, 0, stream>>>(al_s, al_d, rowptr, col, alphaE, denom);
  aggregate_kernel<4,1><<<N, 128, 0, stream>>>(Hb, alphaE, denom, rowptr, col, b2,
                                               (float*)nullptr, feat_hi, feat_lo);

  // ---- layer 3: feat[N,512] @ W3[512,512], heads=1 ----
  wsplit_kernel<<<dim3(F/32, F/32), 256, 0, stream>>>(W3, Bth, Btl, F, F);
  gemm_mfma<<<ggrid, 128, 0, stream>>>(feat_hi, feat_lo, Bth, Btl, Hmat, N, F, F);
  attn_coef_kernel<1,512><<<N, 128, 0, stream>>>(Hmat, as3, ad3, al_s, al_d, Hb);
  alpha_kernel<1><<<N, 64, 0, stream>>>(al_s, al_d, rowptr, col, alphaE, denom);
  aggregate_kernel<1,0><<<N, 128, 0, stream>>>(Hb, alphaE, denom, rowptr, col, b3,
                                               out, (__bf16*)nullptr, (__bf16*)nullptr);
}

// Round 8
// 409.073 us; speedup vs baseline: 1.0672x; 1.0672x over previous
//
#include <hip/hip_runtime.h>

#define NSLOPE 0.2f

typedef __bf16 bf16x8 __attribute__((ext_vector_type(8)));
typedef __bf16 bf16x4 __attribute__((ext_vector_type(4)));
typedef float  f32x4  __attribute__((ext_vector_type(4)));

typedef uint32_t __attribute__((address_space(1))) gbl_u32;
typedef uint32_t __attribute__((address_space(3))) lds_u32;

// ======================= CSR build (per-launch; ws is re-poisoned) ==========
__global__ void init_cnt_kernel(int* cnt, int n){
  int i = blockIdx.x*blockDim.x + threadIdx.x;
  if (i < n) cnt[i] = 1;                       // count the self-loop up front
}

__global__ void hist_kernel(const int* __restrict__ ei, int E, int* cnt){
  int e = blockIdx.x*blockDim.x + threadIdx.x;
  if (e < E) atomicAdd(&cnt[ei[E + e]], 1);    // dst row of edge_index
}

// single-block scan, wave-shuffle based
__global__ void scan_kernel(const int* __restrict__ cnt, int* __restrict__ rowptr,
                            int* __restrict__ cursor, int n){
  __shared__ int wsum[16];
  __shared__ int carry, chunk_total;
  int t = threadIdx.x, lane = t & 63, wid = t >> 6;
  if (t == 0) carry = 0;
  __syncthreads();
  for (int base = 0; base < n; base += 1024){
    int idx = base + t;
    int v = (idx < n) ? cnt[idx] : 0;
    int inc = v;
#pragma unroll
    for (int off = 1; off < 64; off <<= 1){
      int u = __shfl_up(inc, off);
      if (lane >= off) inc += u;
    }
    if (lane == 63) wsum[wid] = inc;
    __syncthreads();
    if (t == 0){
      int s = 0;
#pragma unroll
      for (int i = 0; i < 16; i++){ int x = wsum[i]; wsum[i] = s; s += x; }
      chunk_total = s;
    }
    __syncthreads();
    int excl = carry + wsum[wid] + inc - v;
    if (idx < n){ rowptr[idx] = excl; cursor[idx] = excl; }
    __syncthreads();
    if (t == 0) carry += chunk_total;
    __syncthreads();
  }
  if (t == 0) rowptr[n] = carry;
}

__global__ void fill_kernel(const int* __restrict__ ei, int E, int n,
                            int* cursor, int* __restrict__ col){
  int i = blockIdx.x*blockDim.x + threadIdx.x;
  if (i < E){
    int s = ei[i], d = ei[E + i];
    int slot = atomicAdd(&cursor[d], 1);
    col[slot] = s;
  } else if (i < E + n){
    int v = i - E;                             // self loop (v -> v)
    int slot = atomicAdd(&cursor[v], 1);
    col[slot] = v;
  }
}

// ===== W [K][Nc] fp32 -> B2t [Nc][2K] bf16: hi at [n][k], lo at [n][K+k] ====
__global__ __launch_bounds__(256) void wsplit_kernel(
    const float* __restrict__ W, __bf16* __restrict__ B2t, int K, int Nc){
  __shared__ float hi_s[32][33], lo_s[32][33];
  int tx = threadIdx.x & 31, ty = threadIdx.x >> 5;   // 32 x 8
  int k0 = blockIdx.x * 32, n0 = blockIdx.y * 32;
#pragma unroll
  for (int i = 0; i < 4; i++){
    int r = ty + i*8;
    float v = W[(size_t)(k0 + r)*Nc + n0 + tx];
    float h = (float)(__bf16)v;
    hi_s[r][tx] = h;
    lo_s[r][tx] = v - h;
  }
  __syncthreads();
  int K2 = 2*K;
#pragma unroll
  for (int i = 0; i < 4; i++){
    int n = ty + i*8;
    B2t[(size_t)(n0 + n)*K2 + k0 + tx]     = (__bf16)hi_s[tx][n];
    B2t[(size_t)(n0 + n)*K2 + K + k0 + tx] = (__bf16)lo_s[tx][n];
  }
}

// ===== x [N][128] fp32 -> X2 [N][256] bf16 (hi cols 0..127, lo 128..255) ====
__global__ __launch_bounds__(256) void split_kernel(
    const float* __restrict__ X, __bf16* __restrict__ X2, int total){
  int i = (blockIdx.x*256 + threadIdx.x)*4;
  if (i < total){
    int n = i >> 7, c = i & 127;
    float4 v = *(const float4*)(X + i);
    float f[4] = {v.x, v.y, v.z, v.w};
    bf16x4 h, l;
#pragma unroll
    for (int u = 0; u < 4; u++){
      __bf16 hh = (__bf16)f[u];
      h[u] = hh;
      l[u] = (__bf16)(f[u] - (float)hh);
    }
    *(bf16x4*)(X2 + (size_t)n*256 + c)       = h;
    *(bf16x4*)(X2 + (size_t)n*256 + 128 + c) = l;
  }
}

// ========== standard bf16 MFMA GEMM over K2 = 2K (hi|lo fold) ===============
// C[M][Nc] = A2[M][K2] @ B2t[Nc][K2]^T.  128x128 tile, 256 thr = 4 waves,
// BK=64.  m97 structure: single LDS buffer, global_load_lds width=16,
// 2 barriers/iter.  LDS is fragment-major: block fb (i-subtile, kstep) is
// 1 KiB = 64 lanes x 16 B in MFMA fragment lane order, so one
// global_load_lds per (wave, fb) stages it and ds_read_b128 at
// base+lane*16 reads it back conflict-free.
__global__ __launch_bounds__(256) void gemm_mfma(
    const __bf16* __restrict__ A2, const __bf16* __restrict__ B2t,
    float* __restrict__ C, int M, int Nc, int K2){
  __shared__ uint4 As[1024];   // 16 fb x 64 lanes, 16 KiB
  __shared__ uint4 Bs[1024];   // 16 KiB
  int t = threadIdx.x, w = t >> 6, lane = t & 63;
  int mm = lane & 15, q = lane >> 4;
  int blk = blockIdx.x;
  int bm = (blk >> 2) * 128;          // Nc/128 == 4 always here
  int bn = (blk & 3) * 128;

  // staging: wave w stages fb = w*4+jj (A and B); fb -> i = fb>>1, s = fb&1
  // lane must supply A[i*16 + mm][s*32 + q*8 .. +8)  (16 B)
  const __bf16* gA[4];
  const __bf16* gB[4];
#pragma unroll
  for (int jj = 0; jj < 4; jj++){
    int fb = w*4 + jj;
    int i = fb >> 1, s = fb & 1;
    int rowA = bm + i*16 + mm; rowA = (rowA < M) ? rowA : (M - 1);
    gA[jj] = A2 + (size_t)rowA*K2 + s*32 + q*8;
    int rowB = bn + i*16 + mm;                 // Nc=512 exact, no clamp
    gB[jj] = B2t + (size_t)rowB*K2 + s*32 + q*8;
  }

  f32x4 acc[4][4];
#pragma unroll
  for (int i = 0; i < 4; i++)
#pragma unroll
    for (int j = 0; j < 4; j++)
#pragma unroll
      for (int r = 0; r < 4; r++) acc[i][j][r] = 0.f;

  const int niter = K2 >> 6;
  for (int it = 0; it < niter; it++){
    __syncthreads();                 // previous compute done before restage
#pragma unroll
    for (int jj = 0; jj < 4; jj++){
      int fb = w*4 + jj;
      __builtin_amdgcn_global_load_lds(
          (const gbl_u32*)gA[jj], (lds_u32*)(As + fb*64), 16, 0, 0);
      __builtin_amdgcn_global_load_lds(
          (const gbl_u32*)gB[jj], (lds_u32*)(Bs + fb*64), 16, 0, 0);
      gA[jj] += 64;                  // advance 64 K-elems = 128 B
      gB[jj] += 64;
    }
    __syncthreads();                 // drains vmcnt -> LDS valid
#pragma unroll
    for (int s = 0; s < 2; s++){
      bf16x8 af[4], bfr[4];
#pragma unroll
      for (int i2 = 0; i2 < 4; i2++){
        int fbA = ((((w & 1)*4) + i2) << 1) | s;
        af[i2]  = *(bf16x8*)&As[fbA*64 + lane];
        int fbB = ((((w >> 1)*4) + i2) << 1) | s;
        bfr[i2] = *(bf16x8*)&Bs[fbB*64 + lane];
      }
#pragma unroll
      for (int i2 = 0; i2 < 4; i2++)
#pragma unroll
        for (int j2 = 0; j2 < 4; j2++)
          acc[i2][j2] = __builtin_amdgcn_mfma_f32_16x16x32_bf16(
              af[i2], bfr[j2], acc[i2][j2], 0, 0, 0);
    }
  }

  // ---- store: reg r -> row = q*4 + r, col = mm (within 16x16 subtile) ----
#pragma unroll
  for (int i2 = 0; i2 < 4; i2++){
    int rbase = bm + ((w & 1)*4 + i2)*16 + q*4;
#pragma unroll
    for (int j2 = 0; j2 < 4; j2++){
      int colc = bn + ((w >> 1)*4 + j2)*16 + mm;
#pragma unroll
      for (int r = 0; r < 4; r++){
        int row = rbase + r;
        if (row < M) C[(size_t)row*Nc + colc] = acc[i2][j2][r];
      }
    }
  }
}

// ===== attention coefficients + bf16 copy of H for the gather ==============
template<int H, int CH>
__global__ __launch_bounds__(128) void attn_coef_kernel(
    const float* __restrict__ Hm, const float* __restrict__ asrc,
    const float* __restrict__ adst, float* __restrict__ al_s,
    float* __restrict__ al_d, __bf16* __restrict__ Hb){
  int b = blockIdx.x;                 // n*H + h
  int n = b / H, h = b % H;
  const float* row = Hm + (size_t)n*(H*CH) + (size_t)h*CH;
  int t = threadIdx.x;
  float ss = 0.f, sd = 0.f;
  for (int c = t; c < CH; c += 128){
    float v = row[c];
    Hb[(size_t)b*CH + c] = (__bf16)v;   // same flat layout as Hm
    ss += v * asrc[h*CH + c];
    sd += v * adst[h*CH + c];
  }
#pragma unroll
  for (int off = 32; off > 0; off >>= 1){
    ss += __shfl_down(ss, off);
    sd += __shfl_down(sd, off);
  }
  __shared__ float r0[2], r1[2];
  int wave = t >> 6, lane = t & 63;
  if (lane == 0){ r0[wave] = ss; r1[wave] = sd; }
  __syncthreads();
  if (t == 0){ al_s[b] = r0[0] + r0[1]; al_d[b] = r1[0] + r1[1]; }
}

// ========== per-dst softmax: one WAVE per node, shuffle-only ================
template<int H>
__global__ __launch_bounds__(64) void alpha_kernel(
    const float* __restrict__ al_s, const float* __restrict__ al_d,
    const int* __restrict__ rowptr, const int* __restrict__ col,
    float* __restrict__ alphaE, float* __restrict__ denom){
  int d = blockIdx.x;
  int lane = threadIdx.x;              // 0..63
  int start = rowptr[d], end = rowptr[d + 1];

  float ald[H];
#pragma unroll
  for (int h = 0; h < H; h++) ald[h] = al_d[(size_t)d*H + h];

  float mx[H];
#pragma unroll
  for (int h = 0; h < H; h++) mx[h] = -1e30f;
  for (int e = start + lane; e < end; e += 64){
    int s = col[e];
#pragma unroll
    for (int h = 0; h < H; h++){
      float v = al_s[(size_t)s*H + h] + ald[h];
      v = (v > 0.f) ? v : NSLOPE * v;
      mx[h] = fmaxf(mx[h], v);
    }
  }
#pragma unroll
  for (int h = 0; h < H; h++)
#pragma unroll
    for (int off = 32; off > 0; off >>= 1)
      mx[h] = fmaxf(mx[h], __shfl_xor(mx[h], off));

  float sm[H] = {};
  for (int e = start + lane; e < end; e += 64){
    int s = col[e];
#pragma unroll
    for (int h = 0; h < H; h++){
      float v = al_s[(size_t)s*H + h] + ald[h];
      v = (v > 0.f) ? v : NSLOPE * v;
      float ev = __expf(v - mx[h]);
      alphaE[(size_t)e*H + h] = ev;
      sm[h] += ev;
    }
  }
#pragma unroll
  for (int h = 0; h < H; h++)
#pragma unroll
    for (int off = 32; off > 0; off >>= 1)
      sm[h] += __shfl_xor(sm[h], off);
  if (lane == 0){
#pragma unroll
    for (int h = 0; h < H; h++) denom[(size_t)d*H + h] = sm[h];
  }
}

// ====== weighted gather from bf16 rows ======================================
// MODE 0: fp32 out, no ReLU (layer 3).
// MODE 1: ReLU + bf16 hi/lo written into feat2 row (stride 1024: hi@0, lo@512)
template<int H, int MODE>
__global__ __launch_bounds__(128) void aggregate_kernel(
    const __bf16* __restrict__ Hb, const float* __restrict__ alphaE,
    const float* __restrict__ denom, const int* __restrict__ rowptr,
    const int* __restrict__ col, const float* __restrict__ bias,
    float* __restrict__ outF, __bf16* __restrict__ fhi,
    __bf16* __restrict__ flo, int fstride){
  __shared__ int   src_lds[64];
  __shared__ float a_lds[64 * H];
  __shared__ float part[512];

  int d = blockIdx.x;
  int t = threadIdx.x;
  int g = t >> 6, lane = t & 63;
  int start = rowptr[d], end = rowptr[d + 1];
  const int hh = (lane * H) >> 6;              // head of lane's 8 channels
  const bf16x8* __restrict__ Hb8 = (const bf16x8*)Hb;   // row stride = 64

  float a0[8] = {};
  float a1[8] = {};
  for (int c0 = start; c0 < end; c0 += 64){
    int cnt = min(64, end - c0);
    if (t < cnt){
      src_lds[t] = col[c0 + t];
#pragma unroll
      for (int h = 0; h < H; h++)
        a_lds[t*H + h] = alphaE[(size_t)(c0 + t)*H + h];
    }
    __syncthreads();
    int i = g;
    for (; i + 2 < cnt; i += 4){
      int s0 = src_lds[i], s1 = src_lds[i + 2];
      float e0 = a_lds[i*H + hh], e1 = a_lds[(i + 2)*H + hh];
      bf16x8 v0 = Hb8[(size_t)s0*64 + lane];
      bf16x8 v1 = Hb8[(size_t)s1*64 + lane];
#pragma unroll
      for (int u = 0; u < 8; u++){
        a0[u] += e0 * (float)v0[u];
        a1[u] += e1 * (float)v1[u];
      }
    }
    for (; i < cnt; i += 2){
      int s0 = src_lds[i];
      float e0 = a_lds[i*H + hh];
      bf16x8 v0 = Hb8[(size_t)s0*64 + lane];
#pragma unroll
      for (int u = 0; u < 8; u++) a0[u] += e0 * (float)v0[u];
    }
    __syncthreads();
  }

  if (g == 1){
#pragma unroll
    for (int u = 0; u < 8; u++) part[lane*8 + u] = a0[u] + a1[u];
  }
  __syncthreads();
  if (g == 0){
    float inv = 1.f / denom[(size_t)d*H + hh];
    float r[8];
#pragma unroll
    for (int u = 0; u < 8; u++){
      float v = (a0[u] + a1[u] + part[lane*8 + u]) * inv + bias[lane*8 + u];
      if (MODE == 1) v = fmaxf(v, 0.f);
      r[u] = v;
    }
    if (MODE == 1){
      bf16x8 hv, lv;
#pragma unroll
      for (int u = 0; u < 8; u++){
        __bf16 h = (__bf16)r[u];
        hv[u] = h;
        lv[u] = (__bf16)(r[u] - (float)h);
      }
      *(bf16x8*)(fhi + (size_t)d*fstride + lane*8) = hv;
      *(bf16x8*)(flo + (size_t)d*fstride + lane*8) = lv;
    } else {
      float4* op = (float4*)(outF + (size_t)d*512 + lane*8);
      op[0] = make_float4(r[0], r[1], r[2], r[3]);
      op[1] = make_float4(r[4], r[5], r[6], r[7]);
    }
  }
}

// =========================== launch =========================================
extern "C" void kernel_launch(void* const* d_in, const int* in_sizes, int n_in,
                              void* d_out, int out_size, void* d_ws, size_t ws_size,
                              hipStream_t stream){
  const float* x   = (const float*)d_in[0];
  const int*   ei  = (const int*)  d_in[1];
  const float* W1  = (const float*)d_in[2];
  const float* as1 = (const float*)d_in[3];
  const float* ad1 = (const float*)d_in[4];
  const float* b1  = (const float*)d_in[5];
  const float* W2  = (const float*)d_in[6];
  const float* as2 = (const float*)d_in[7];
  const float* ad2 = (const float*)d_in[8];
  const float* b2  = (const float*)d_in[9];
  const float* W3  = (const float*)d_in[10];
  const float* as3 = (const float*)d_in[11];
  const float* ad3 = (const float*)d_in[12];
  const float* b3  = (const float*)d_in[13];
  float* out = (float*)d_out;

  const int N = in_sizes[0] / 128;   // 10000
  const int E = in_sizes[1] / 2;     // 320000
  const int F = 512;
  const int Etot = E + N;

  // workspace carve-up
  float*  Hmat   = (float*)d_ws;                      // N*512 fp32
  __bf16* feat2  = (__bf16*)(Hmat + (size_t)N*F);     // N*1024 bf16 (hi|lo)
  float*  al_s   = (float*)(feat2 + (size_t)N*1024);  // N*4
  float*  al_d   = al_s + (size_t)N*4;                // N*4
  float*  alphaE = al_d + (size_t)N*4;                // (E+N)*4
  float*  denom  = alphaE + (size_t)Etot*4;           // N*4
  int*    cnt    = (int*)(denom + (size_t)N*4);       // N
  int*    rowptr = cnt + N;                           // N+1
  int*    cursor = rowptr + N + 1;                    // N
  int*    col    = cursor + N;                        // E+N
  uintptr_t p  = (uintptr_t)(col + Etot);
  p = (p + 15) & ~(uintptr_t)15;
  __bf16* B2t = (__bf16*)p;                           // 512*1024 bf16
  __bf16* Hb  = B2t + 512*1024;                       // N*512 bf16 (gather)
  // X2 (N*256 bf16 = 5.12 MB) aliases alphaE region (5.28 MB): consumed by
  // the layer-1 gemm BEFORE alpha_kernel first writes alphaE.
  __bf16* X2 = (__bf16*)alphaE;

  // CSR by destination
  init_cnt_kernel<<<(N+255)/256, 256, 0, stream>>>(cnt, N);
  hist_kernel<<<(E+255)/256, 256, 0, stream>>>(ei, E, cnt);
  scan_kernel<<<1, 1024, 0, stream>>>(cnt, rowptr, cursor, N);
  fill_kernel<<<(E+N+255)/256, 256, 0, stream>>>(ei, E, N, cursor, col);

  const int ggrid = ((N + 127)/128) * (F/128);   // 79 * 4 = 316 blocks

  // ---- layer 1: x[N,128] @ W1[128,512]  (K2 = 256) ----
  split_kernel<<<(N*128/4 + 255)/256, 256, 0, stream>>>(x, X2, N*128);
  wsplit_kernel<<<dim3(128/32, F/32), 256, 0, stream>>>(W1, B2t, 128, F);
  gemm_mfma<<<ggrid, 256, 0, stream>>>(X2, B2t, Hmat, N, F, 256);
  attn_coef_kernel<4,128><<<N*4, 128, 0, stream>>>(Hmat, as1, ad1, al_s, al_d, Hb);
  alpha_kernel<4><<<N, 64, 0, stream>>>(al_s, al_d, rowptr, col, alphaE, denom);
  aggregate_kernel<4,1><<<N, 128, 0, stream>>>(Hb, alphaE, denom, rowptr, col, b1,
                                               (float*)nullptr, feat2, feat2 + 512, 1024);

  // ---- layer 2: feat[N,512] @ W2[512,512]  (K2 = 1024) ----
  wsplit_kernel<<<dim3(F/32, F/32), 256, 0, stream>>>(W2, B2t, F, F);
  gemm_mfma<<<ggrid, 256, 0, stream>>>(feat2, B2t, Hmat, N, F, 1024);
  attn_coef_kernel<4,128><<<N*4, 128, 0, stream>>>(Hmat, as2, ad2, al_s, al_d, Hb);
  alpha_kernel<4><<<N, 64, 0, stream>>>(al_s, al_d, rowptr, col, alphaE, denom);
  aggregate_kernel<4,1><<<N, 128, 0, stream>>>(Hb, alphaE, denom, rowptr, col, b2,
                                               (float*)nullptr, feat2, feat2 + 512, 1024);

  // ---- layer 3: feat[N,512] @ W3[512,512], heads=1  (K2 = 1024) ----
  wsplit_kernel<<<dim3(F/32, F/32), 256, 0, stream>>>(W3, B2t, F, F);
  gemm_mfma<<<ggrid, 256, 0, stream>>>(feat2, B2t, Hmat, N, F, 1024);
  attn_coef_kernel<1,512><<<N, 128, 0, stream>>>(Hmat, as3, ad3, al_s, al_d, Hb);
  alpha_kernel<1><<<N, 64, 0, stream>>>(al_s, al_d, rowptr, col, alphaE, denom);
  aggregate_kernel<1,0><<<N, 128, 0, stream>>>(Hb, alphaE, denom, rowptr, col, b3,
                                               out, (__bf16*)nullptr, (__bf16*)nullptr, 0);
}

// Round 9
// 382.317 us; speedup vs baseline: 1.1419x; 1.0700x over previous
//
#include <hip/hip_runtime.h>

#define NSLOPE 0.2f

typedef __bf16 bf16x8 __attribute__((ext_vector_type(8)));
typedef __bf16 bf16x4 __attribute__((ext_vector_type(4)));
typedef __bf16 bf16x2 __attribute__((ext_vector_type(2)));
typedef float  f32x4  __attribute__((ext_vector_type(4)));

typedef uint32_t __attribute__((address_space(1))) gbl_u32;
typedef uint32_t __attribute__((address_space(3))) lds_u32;

// ======================= CSR build (per-launch; ws is re-poisoned) ==========
__global__ void init_cnt_kernel(int* cnt, int n){
  int i = blockIdx.x*blockDim.x + threadIdx.x;
  if (i < n) cnt[i] = 1;                       // count the self-loop up front
}

__global__ void hist_kernel(const int* __restrict__ ei, int E, int* cnt){
  int e = blockIdx.x*blockDim.x + threadIdx.x;
  if (e < E) atomicAdd(&cnt[ei[E + e]], 1);    // dst row of edge_index
}

// single-block scan, wave-shuffle based
__global__ void scan_kernel(const int* __restrict__ cnt, int* __restrict__ rowptr,
                            int* __restrict__ cursor, int n){
  __shared__ int wsum[16];
  __shared__ int carry, chunk_total;
  int t = threadIdx.x, lane = t & 63, wid = t >> 6;
  if (t == 0) carry = 0;
  __syncthreads();
  for (int base = 0; base < n; base += 1024){
    int idx = base + t;
    int v = (idx < n) ? cnt[idx] : 0;
    int inc = v;
#pragma unroll
    for (int off = 1; off < 64; off <<= 1){
      int u = __shfl_up(inc, off);
      if (lane >= off) inc += u;
    }
    if (lane == 63) wsum[wid] = inc;
    __syncthreads();
    if (t == 0){
      int s = 0;
#pragma unroll
      for (int i = 0; i < 16; i++){ int x = wsum[i]; wsum[i] = s; s += x; }
      chunk_total = s;
    }
    __syncthreads();
    int excl = carry + wsum[wid] + inc - v;
    if (idx < n){ rowptr[idx] = excl; cursor[idx] = excl; }
    __syncthreads();
    if (t == 0) carry += chunk_total;
    __syncthreads();
  }
  if (t == 0) rowptr[n] = carry;
}

__global__ void fill_kernel(const int* __restrict__ ei, int E, int n,
                            int* cursor, int* __restrict__ col){
  int i = blockIdx.x*blockDim.x + threadIdx.x;
  if (i < E){
    int s = ei[i], d = ei[E + i];
    int slot = atomicAdd(&cursor[d], 1);
    col[slot] = s;
  } else if (i < E + n){
    int v = i - E;                             // self loop (v -> v)
    int slot = atomicAdd(&cursor[v], 1);
    col[slot] = v;
  }
}

// ===== W [K][Nc] fp32 -> B2t [Nc][2K] bf16: hi at [n][k], lo at [n][K+k] ====
__global__ __launch_bounds__(256) void wsplit_kernel(
    const float* __restrict__ W, __bf16* __restrict__ B2t, int K, int Nc){
  __shared__ float hi_s[32][33], lo_s[32][33];
  int tx = threadIdx.x & 31, ty = threadIdx.x >> 5;   // 32 x 8
  int k0 = blockIdx.x * 32, n0 = blockIdx.y * 32;
#pragma unroll
  for (int i = 0; i < 4; i++){
    int r = ty + i*8;
    float v = W[(size_t)(k0 + r)*Nc + n0 + tx];
    float h = (float)(__bf16)v;
    hi_s[r][tx] = h;
    lo_s[r][tx] = v - h;
  }
  __syncthreads();
  int K2 = 2*K;
#pragma unroll
  for (int i = 0; i < 4; i++){
    int n = ty + i*8;
    B2t[(size_t)(n0 + n)*K2 + k0 + tx]     = (__bf16)hi_s[tx][n];
    B2t[(size_t)(n0 + n)*K2 + K + k0 + tx] = (__bf16)lo_s[tx][n];
  }
}

// ===== x [N][128] fp32 -> X2 [N][256] bf16 (hi cols 0..127, lo 128..255) ====
__global__ __launch_bounds__(256) void split_kernel(
    const float* __restrict__ X, __bf16* __restrict__ X2, int total){
  int i = (blockIdx.x*256 + threadIdx.x)*4;
  if (i < total){
    int n = i >> 7, c = i & 127;
    float4 v = *(const float4*)(X + i);
    float f[4] = {v.x, v.y, v.z, v.w};
    bf16x4 h, l;
#pragma unroll
    for (int u = 0; u < 4; u++){
      __bf16 hh = (__bf16)f[u];
      h[u] = hh;
      l[u] = (__bf16)(f[u] - (float)hh);
    }
    *(bf16x4*)(X2 + (size_t)n*256 + c)       = h;
    *(bf16x4*)(X2 + (size_t)n*256 + 128 + c) = l;
  }
}

// ========== standard bf16 MFMA GEMM over K2 = 2K (hi|lo fold) ===============
// m97 structure: 128x128 tile, 256 thr, single LDS buffer, global_load_lds
// width=16, 2 barriers/iter, fragment-major LDS (conflict-free both ways).
__global__ __launch_bounds__(256) void gemm_mfma(
    const __bf16* __restrict__ A2, const __bf16* __restrict__ B2t,
    float* __restrict__ C, int M, int Nc, int K2){
  __shared__ uint4 As[1024];   // 16 fb x 64 lanes, 16 KiB
  __shared__ uint4 Bs[1024];   // 16 KiB
  int t = threadIdx.x, w = t >> 6, lane = t & 63;
  int mm = lane & 15, q = lane >> 4;
  int blk = blockIdx.x;
  int bm = (blk >> 2) * 128;          // Nc/128 == 4 always here
  int bn = (blk & 3) * 128;

  const __bf16* gA[4];
  const __bf16* gB[4];
#pragma unroll
  for (int jj = 0; jj < 4; jj++){
    int fb = w*4 + jj;
    int i = fb >> 1, s = fb & 1;
    int rowA = bm + i*16 + mm; rowA = (rowA < M) ? rowA : (M - 1);
    gA[jj] = A2 + (size_t)rowA*K2 + s*32 + q*8;
    int rowB = bn + i*16 + mm;
    gB[jj] = B2t + (size_t)rowB*K2 + s*32 + q*8;
  }

  f32x4 acc[4][4];
#pragma unroll
  for (int i = 0; i < 4; i++)
#pragma unroll
    for (int j = 0; j < 4; j++)
#pragma unroll
      for (int r = 0; r < 4; r++) acc[i][j][r] = 0.f;

  const int niter = K2 >> 6;
  for (int it = 0; it < niter; it++){
    __syncthreads();
#pragma unroll
    for (int jj = 0; jj < 4; jj++){
      int fb = w*4 + jj;
      __builtin_amdgcn_global_load_lds(
          (const gbl_u32*)gA[jj], (lds_u32*)(As + fb*64), 16, 0, 0);
      __builtin_amdgcn_global_load_lds(
          (const gbl_u32*)gB[jj], (lds_u32*)(Bs + fb*64), 16, 0, 0);
      gA[jj] += 64;
      gB[jj] += 64;
    }
    __syncthreads();
#pragma unroll
    for (int s = 0; s < 2; s++){
      bf16x8 af[4], bfr[4];
#pragma unroll
      for (int i2 = 0; i2 < 4; i2++){
        int fbA = ((((w & 1)*4) + i2) << 1) | s;
        af[i2]  = *(bf16x8*)&As[fbA*64 + lane];
        int fbB = ((((w >> 1)*4) + i2) << 1) | s;
        bfr[i2] = *(bf16x8*)&Bs[fbB*64 + lane];
      }
#pragma unroll
      for (int i2 = 0; i2 < 4; i2++)
#pragma unroll
        for (int j2 = 0; j2 < 4; j2++)
          acc[i2][j2] = __builtin_amdgcn_mfma_f32_16x16x32_bf16(
              af[i2], bfr[j2], acc[i2][j2], 0, 0, 0);
    }
  }

#pragma unroll
  for (int i2 = 0; i2 < 4; i2++){
    int rbase = bm + ((w & 1)*4 + i2)*16 + q*4;
#pragma unroll
    for (int j2 = 0; j2 < 4; j2++){
      int colc = bn + ((w >> 1)*4 + j2)*16 + mm;
#pragma unroll
      for (int r = 0; r < 4; r++){
        int row = rbase + r;
        if (row < M) C[(size_t)row*Nc + colc] = acc[i2][j2][r];
      }
    }
  }
}

// ===== attention coefficients + bf16 copy of H for the gather ==============
template<int H, int CH>
__global__ __launch_bounds__(128) void attn_coef_kernel(
    const float* __restrict__ Hm, const float* __restrict__ asrc,
    const float* __restrict__ adst, float* __restrict__ al_s,
    float* __restrict__ al_d, __bf16* __restrict__ Hb){
  int b = blockIdx.x;                 // n*H + h
  int n = b / H, h = b % H;
  const float* row = Hm + (size_t)n*(H*CH) + (size_t)h*CH;
  int t = threadIdx.x;
  float ss = 0.f, sd = 0.f;
  for (int c = t; c < CH; c += 128){
    float v = row[c];
    Hb[(size_t)b*CH + c] = (__bf16)v;   // same flat layout as Hm
    ss += v * asrc[h*CH + c];
    sd += v * adst[h*CH + c];
  }
#pragma unroll
  for (int off = 32; off > 0; off >>= 1){
    ss += __shfl_down(ss, off);
    sd += __shfl_down(sd, off);
  }
  __shared__ float r0[2], r1[2];
  int wave = t >> 6, lane = t & 63;
  if (lane == 0){ r0[wave] = ss; r1[wave] = sd; }
  __syncthreads();
  if (t == 0){ al_s[b] = r0[0] + r0[1]; al_d[b] = r1[0] + r1[1]; }
}

// ========== per-dst softmax: one WAVE per node, shuffle-only ================
// alphaE layout: [H][Etot] (transposed) so per-head slices are contiguous.
template<int H>
__global__ __launch_bounds__(64) void alpha_kernel(
    const float* __restrict__ al_s, const float* __restrict__ al_d,
    const int* __restrict__ rowptr, const int* __restrict__ col,
    float* __restrict__ alphaE, float* __restrict__ denom, int Etot){
  int d = blockIdx.x;
  int lane = threadIdx.x;              // 0..63
  int start = rowptr[d], end = rowptr[d + 1];

  float ald[H];
#pragma unroll
  for (int h = 0; h < H; h++) ald[h] = al_d[(size_t)d*H + h];

  float mx[H];
#pragma unroll
  for (int h = 0; h < H; h++) mx[h] = -1e30f;
  for (int e = start + lane; e < end; e += 64){
    int s = col[e];
#pragma unroll
    for (int h = 0; h < H; h++){
      float v = al_s[(size_t)s*H + h] + ald[h];
      v = (v > 0.f) ? v : NSLOPE * v;
      mx[h] = fmaxf(mx[h], v);
    }
  }
#pragma unroll
  for (int h = 0; h < H; h++)
#pragma unroll
    for (int off = 32; off > 0; off >>= 1)
      mx[h] = fmaxf(mx[h], __shfl_xor(mx[h], off));

  float sm[H] = {};
  for (int e = start + lane; e < end; e += 64){
    int s = col[e];
#pragma unroll
    for (int h = 0; h < H; h++){
      float v = al_s[(size_t)s*H + h] + ald[h];
      v = (v > 0.f) ? v : NSLOPE * v;
      float ev = __expf(v - mx[h]);
      alphaE[(size_t)h*Etot + e] = ev;
      sm[h] += ev;
    }
  }
#pragma unroll
  for (int h = 0; h < H; h++)
#pragma unroll
    for (int off = 32; off > 0; off >>= 1)
      sm[h] += __shfl_xor(sm[h], off);
  if (lane == 0){
#pragma unroll
    for (int h = 0; h < H; h++) denom[(size_t)d*H + h] = sm[h];
  }
}

// ====== channel-sliced weighted gather, XCD-pinned ==========================
// grid g = idx*8 + x; x = (slice<<1)|half -> XCD x (blockIdx%8 round-robin).
// slice s = 128 channels (256 B/row): per-slice working set N*256B = 2.56 MB
// fits one XCD's 4 MB L2 -> gather becomes L2-hit after compulsory fill.
// One wave per (node, slice); lane owns 2 channels (bf16x2 = 4B, coalesced).
// For H=4, slice == head; for H=1, head = 0.
// MODE 0: fp32 out, no ReLU.  MODE 1: ReLU + bf16 hi/lo into feat2 row.
template<int H, int MODE>
__global__ __launch_bounds__(64) void aggregate_slice(
    const __bf16* __restrict__ Hb, const float* __restrict__ alphaE,
    const float* __restrict__ denom, const int* __restrict__ rowptr,
    const int* __restrict__ col, const float* __restrict__ bias,
    float* __restrict__ outF, __bf16* __restrict__ fhi,
    __bf16* __restrict__ flo, int fstride, int nidx, int N, int Etot){
  int g = blockIdx.x;
  int x = g & 7, idx = g >> 3;
  int s = x >> 1, half = x & 1;
  int d = half * nidx + idx;
  if (d >= N) return;
  int lane = threadIdx.x;
  int start = rowptr[d], end = rowptr[d + 1];
  const int hh = (H == 1) ? 0 : s;
  const float* __restrict__ aE = alphaE + (size_t)hh*Etot;
  const bf16x2* __restrict__ Hb2 = (const bf16x2*)Hb;   // row = 256 units
  const size_t coff = s*64 + lane;

  __shared__ int   src_s[64];
  __shared__ float a_s[64];

  float ax0=0.f, ay0=0.f, ax1=0.f, ay1=0.f;
  float ax2=0.f, ay2=0.f, ax3=0.f, ay3=0.f;

  for (int c0 = start; c0 < end; c0 += 64){
    int cnt = min(64, end - c0);
    if (lane < cnt){
      int e = c0 + lane;
      src_s[lane] = col[e];
      a_s[lane]   = aE[e];
    }
    __syncthreads();                  // 1 wave: compiles to waitcnt
    int i = 0;
    for (; i + 4 <= cnt; i += 4){
      int s0 = src_s[i],   s1 = src_s[i+1];
      int s2 = src_s[i+2], s3 = src_s[i+3];
      float e0 = a_s[i],   e1 = a_s[i+1];
      float e2 = a_s[i+2], e3 = a_s[i+3];
      bf16x2 v0 = Hb2[(size_t)s0*256 + coff];
      bf16x2 v1 = Hb2[(size_t)s1*256 + coff];
      bf16x2 v2 = Hb2[(size_t)s2*256 + coff];
      bf16x2 v3 = Hb2[(size_t)s3*256 + coff];
      ax0 += e0*(float)v0[0]; ay0 += e0*(float)v0[1];
      ax1 += e1*(float)v1[0]; ay1 += e1*(float)v1[1];
      ax2 += e2*(float)v2[0]; ay2 += e2*(float)v2[1];
      ax3 += e3*(float)v3[0]; ay3 += e3*(float)v3[1];
    }
    for (; i < cnt; i++){
      int s0 = src_s[i];
      float e0 = a_s[i];
      bf16x2 v0 = Hb2[(size_t)s0*256 + coff];
      ax0 += e0*(float)v0[0]; ay0 += e0*(float)v0[1];
    }
    __syncthreads();
  }

  float accx = (ax0 + ax1) + (ax2 + ax3);
  float accy = (ay0 + ay1) + (ay2 + ay3);
  float invd = 1.f / denom[(size_t)d*H + hh];
  int c = s*128 + lane*2;
  float2 bv = *(const float2*)(bias + c);
  float r0 = accx * invd + bv.x;
  float r1 = accy * invd + bv.y;
  if (MODE == 1){
    r0 = fmaxf(r0, 0.f); r1 = fmaxf(r1, 0.f);
    __bf16 h0 = (__bf16)r0, h1 = (__bf16)r1;
    bf16x2 hv; hv[0] = h0; hv[1] = h1;
    bf16x2 lv; lv[0] = (__bf16)(r0 - (float)h0); lv[1] = (__bf16)(r1 - (float)h1);
    *(bf16x2*)(fhi + (size_t)d*fstride + c) = hv;
    *(bf16x2*)(flo + (size_t)d*fstride + c) = lv;
  } else {
    *(float2*)(outF + (size_t)d*512 + c) = make_float2(r0, r1);
  }
}

// =========================== launch =========================================
extern "C" void kernel_launch(void* const* d_in, const int* in_sizes, int n_in,
                              void* d_out, int out_size, void* d_ws, size_t ws_size,
                              hipStream_t stream){
  const float* x   = (const float*)d_in[0];
  const int*   ei  = (const int*)  d_in[1];
  const float* W1  = (const float*)d_in[2];
  const float* as1 = (const float*)d_in[3];
  const float* ad1 = (const float*)d_in[4];
  const float* b1  = (const float*)d_in[5];
  const float* W2  = (const float*)d_in[6];
  const float* as2 = (const float*)d_in[7];
  const float* ad2 = (const float*)d_in[8];
  const float* b2  = (const float*)d_in[9];
  const float* W3  = (const float*)d_in[10];
  const float* as3 = (const float*)d_in[11];
  const float* ad3 = (const float*)d_in[12];
  const float* b3  = (const float*)d_in[13];
  float* out = (float*)d_out;

  const int N = in_sizes[0] / 128;   // 10000
  const int E = in_sizes[1] / 2;     // 320000
  const int F = 512;
  const int Etot = E + N;
  const int nidx = (N + 1) / 2;

  // workspace carve-up
  float*  Hmat   = (float*)d_ws;                      // N*512 fp32
  __bf16* feat2  = (__bf16*)(Hmat + (size_t)N*F);     // N*1024 bf16 (hi|lo)
  float*  al_s   = (float*)(feat2 + (size_t)N*1024);  // N*4
  float*  al_d   = al_s + (size_t)N*4;                // N*4
  float*  alphaE = al_d + (size_t)N*4;                // [H][E+N] = (E+N)*4
  float*  denom  = alphaE + (size_t)Etot*4;           // N*4
  int*    cnt    = (int*)(denom + (size_t)N*4);       // N
  int*    rowptr = cnt + N;                           // N+1
  int*    cursor = rowptr + N + 1;                    // N
  int*    col    = cursor + N;                        // E+N
  uintptr_t p  = (uintptr_t)(col + Etot);
  p = (p + 15) & ~(uintptr_t)15;
  __bf16* B2t = (__bf16*)p;                           // 512*1024 bf16
  __bf16* Hb  = B2t + 512*1024;                       // N*512 bf16 (gather)
  // X2 (N*256 bf16 = 5.12 MB) aliases alphaE region (5.28 MB): consumed by
  // the layer-1 gemm BEFORE alpha_kernel first writes alphaE.
  __bf16* X2 = (__bf16*)alphaE;

  // CSR by destination
  init_cnt_kernel<<<(N+255)/256, 256, 0, stream>>>(cnt, N);
  hist_kernel<<<(E+255)/256, 256, 0, stream>>>(ei, E, cnt);
  scan_kernel<<<1, 1024, 0, stream>>>(cnt, rowptr, cursor, N);
  fill_kernel<<<(E+N+255)/256, 256, 0, stream>>>(ei, E, N, cursor, col);

  const int ggrid = ((N + 127)/128) * (F/128);   // 79 * 4 = 316 blocks
  const int agrid = nidx * 8;

  // ---- layer 1: x[N,128] @ W1[128,512]  (K2 = 256) ----
  split_kernel<<<(N*128/4 + 255)/256, 256, 0, stream>>>(x, X2, N*128);
  wsplit_kernel<<<dim3(128/32, F/32), 256, 0, stream>>>(W1, B2t, 128, F);
  gemm_mfma<<<ggrid, 256, 0, stream>>>(X2, B2t, Hmat, N, F, 256);
  attn_coef_kernel<4,128><<<N*4, 128, 0, stream>>>(Hmat, as1, ad1, al_s, al_d, Hb);
  alpha_kernel<4><<<N, 64, 0, stream>>>(al_s, al_d, rowptr, col, alphaE, denom, Etot);
  aggregate_slice<4,1><<<agrid, 64, 0, stream>>>(Hb, alphaE, denom, rowptr, col, b1,
      (float*)nullptr, feat2, feat2 + 512, 1024, nidx, N, Etot);

  // ---- layer 2: feat[N,512] @ W2[512,512]  (K2 = 1024) ----
  wsplit_kernel<<<dim3(F/32, F/32), 256, 0, stream>>>(W2, B2t, F, F);
  gemm_mfma<<<ggrid, 256, 0, stream>>>(feat2, B2t, Hmat, N, F, 1024);
  attn_coef_kernel<4,128><<<N*4, 128, 0, stream>>>(Hmat, as2, ad2, al_s, al_d, Hb);
  alpha_kernel<4><<<N, 64, 0, stream>>>(al_s, al_d, rowptr, col, alphaE, denom, Etot);
  aggregate_slice<4,1><<<agrid, 64, 0, stream>>>(Hb, alphaE, denom, rowptr, col, b2,
      (float*)nullptr, feat2, feat2 + 512, 1024, nidx, N, Etot);

  // ---- layer 3: feat[N,512] @ W3[512,512], heads=1  (K2 = 1024) ----
  wsplit_kernel<<<dim3(F/32, F/32), 256, 0, stream>>>(W3, B2t, F, F);
  gemm_mfma<<<ggrid, 256, 0, stream>>>(feat2, B2t, Hmat, N, F, 1024);
  attn_coef_kernel<1,512><<<N, 128, 0, stream>>>(Hmat, as3, ad3, al_s, al_d, Hb);
  alpha_kernel<1><<<N, 64, 0, stream>>>(al_s, al_d, rowptr, col, alphaE, denom, Etot);
  aggregate_slice<1,0><<<agrid, 64, 0, stream>>>(Hb, alphaE, denom, rowptr, col, b3,
      out, (__bf16*)nullptr, (__bf16*)nullptr, 0, nidx, N, Etot);
}

// Round 10
// 370.266 us; speedup vs baseline: 1.1791x; 1.0325x over previous
//
#include <hip/hip_runtime.h>

#define NSLOPE 0.2f

typedef __bf16 bf16x8 __attribute__((ext_vector_type(8)));
typedef __bf16 bf16x4 __attribute__((ext_vector_type(4)));
typedef __bf16 bf16x2 __attribute__((ext_vector_type(2)));
typedef float  f32x4  __attribute__((ext_vector_type(4)));

typedef uint32_t __attribute__((address_space(1))) gbl_u32;
typedef uint32_t __attribute__((address_space(3))) lds_u32;

// ======================= CSR build (per-launch; ws is re-poisoned) ==========
__global__ void init_cnt_kernel(int* cnt, int n){
  int i = blockIdx.x*blockDim.x + threadIdx.x;
  if (i < n) cnt[i] = 1;                       // count the self-loop up front
}

__global__ void hist_kernel(const int* __restrict__ ei, int E, int* cnt){
  int e = blockIdx.x*blockDim.x + threadIdx.x;
  if (e < E) atomicAdd(&cnt[ei[E + e]], 1);    // dst row of edge_index
}

// single-block scan, wave-shuffle based
__global__ void scan_kernel(const int* __restrict__ cnt, int* __restrict__ rowptr,
                            int* __restrict__ cursor, int n){
  __shared__ int wsum[16];
  __shared__ int carry, chunk_total;
  int t = threadIdx.x, lane = t & 63, wid = t >> 6;
  if (t == 0) carry = 0;
  __syncthreads();
  for (int base = 0; base < n; base += 1024){
    int idx = base + t;
    int v = (idx < n) ? cnt[idx] : 0;
    int inc = v;
#pragma unroll
    for (int off = 1; off < 64; off <<= 1){
      int u = __shfl_up(inc, off);
      if (lane >= off) inc += u;
    }
    if (lane == 63) wsum[wid] = inc;
    __syncthreads();
    if (t == 0){
      int s = 0;
#pragma unroll
      for (int i = 0; i < 16; i++){ int x = wsum[i]; wsum[i] = s; s += x; }
      chunk_total = s;
    }
    __syncthreads();
    int excl = carry + wsum[wid] + inc - v;
    if (idx < n){ rowptr[idx] = excl; cursor[idx] = excl; }
    __syncthreads();
    if (t == 0) carry += chunk_total;
    __syncthreads();
  }
  if (t == 0) rowptr[n] = carry;
}

__global__ void fill_kernel(const int* __restrict__ ei, int E, int n,
                            int* cursor, int* __restrict__ col){
  int i = blockIdx.x*blockDim.x + threadIdx.x;
  if (i < E){
    int s = ei[i], d = ei[E + i];
    int slot = atomicAdd(&cursor[d], 1);
    col[slot] = s;
  } else if (i < E + n){
    int v = i - E;                             // self loop (v -> v)
    int slot = atomicAdd(&cursor[v], 1);
    col[slot] = v;
  }
}

// ===== W [K][Nc] fp32 -> B2t [Nc][2K] bf16 (hi|lo), + zero al_s/al_d ========
__global__ __launch_bounds__(256) void wsplit_kernel(
    const float* __restrict__ W, __bf16* __restrict__ B2t, int K, int Nc,
    float* __restrict__ al_s, float* __restrict__ al_d, int nzero){
  __shared__ float hi_s[32][33], lo_s[32][33];
  int tx = threadIdx.x & 31, ty = threadIdx.x >> 5;   // 32 x 8
  int k0 = blockIdx.x * 32, n0 = blockIdx.y * 32;
  // grid-stride zero of the attention-coefficient accumulators
  {
    int bid = blockIdx.y * gridDim.x + blockIdx.x;
    int gtid = bid * 256 + threadIdx.x;
    int stride = gridDim.x * gridDim.y * 256;
    for (int i = gtid; i < nzero; i += stride){ al_s[i] = 0.f; al_d[i] = 0.f; }
  }
#pragma unroll
  for (int i = 0; i < 4; i++){
    int r = ty + i*8;
    float v = W[(size_t)(k0 + r)*Nc + n0 + tx];
    float h = (float)(__bf16)v;
    hi_s[r][tx] = h;
    lo_s[r][tx] = v - h;
  }
  __syncthreads();
  int K2 = 2*K;
#pragma unroll
  for (int i = 0; i < 4; i++){
    int n = ty + i*8;
    B2t[(size_t)(n0 + n)*K2 + k0 + tx]     = (__bf16)hi_s[tx][n];
    B2t[(size_t)(n0 + n)*K2 + K + k0 + tx] = (__bf16)lo_s[tx][n];
  }
}

// ===== x [N][128] fp32 -> X2 [N][256] bf16 (hi cols 0..127, lo 128..255) ====
__global__ __launch_bounds__(256) void split_kernel(
    const float* __restrict__ X, __bf16* __restrict__ X2, int total){
  int i = (blockIdx.x*256 + threadIdx.x)*4;
  if (i < total){
    int n = i >> 7, c = i & 127;
    float4 v = *(const float4*)(X + i);
    float f[4] = {v.x, v.y, v.z, v.w};
    bf16x4 h, l;
#pragma unroll
    for (int u = 0; u < 4; u++){
      __bf16 hh = (__bf16)f[u];
      h[u] = hh;
      l[u] = (__bf16)(f[u] - (float)hh);
    }
    *(bf16x4*)(X2 + (size_t)n*256 + c)       = h;
    *(bf16x4*)(X2 + (size_t)n*256 + 128 + c) = l;
  }
}

// ========== bf16 MFMA GEMM over K2=2K, fused attention-coef epilogue ========
// m97 structure: 128x128 tile, 256 thr, single LDS buffer, global_load_lds
// width=16, 2 barriers/iter, fragment-major LDS (conflict-free both ways).
// Epilogue: writes Hb bf16 (no fp32 C), and per-row dot products with
// a_src/a_dst reduced via quarter-wave shuffles + one atomicAdd per (row,wave).
// For H=4 a 128-col block is exactly one head (bn>>7); H=1 -> head 0.
template<int H>
__global__ __launch_bounds__(256) void gemm_mfma(
    const __bf16* __restrict__ A2, const __bf16* __restrict__ B2t,
    __bf16* __restrict__ Hb, const float* __restrict__ asrc,
    const float* __restrict__ adst, float* __restrict__ al_s,
    float* __restrict__ al_d, int M, int Nc, int K2){
  __shared__ uint4 As[1024];   // 16 fb x 64 lanes, 16 KiB
  __shared__ uint4 Bs[1024];   // 16 KiB
  int t = threadIdx.x, w = t >> 6, lane = t & 63;
  int mm = lane & 15, q = lane >> 4;
  int blk = blockIdx.x;
  int bm = (blk >> 2) * 128;          // Nc/128 == 4 always here
  int bn = (blk & 3) * 128;

  const __bf16* gA[4];
  const __bf16* gB[4];
#pragma unroll
  for (int jj = 0; jj < 4; jj++){
    int fb = w*4 + jj;
    int i = fb >> 1, s = fb & 1;
    int rowA = bm + i*16 + mm; rowA = (rowA < M) ? rowA : (M - 1);
    gA[jj] = A2 + (size_t)rowA*K2 + s*32 + q*8;
    int rowB = bn + i*16 + mm;
    gB[jj] = B2t + (size_t)rowB*K2 + s*32 + q*8;
  }

  // per-lane a_src/a_dst for this lane's 4 columns
  float asv[4], adv[4];
#pragma unroll
  for (int j2 = 0; j2 < 4; j2++){
    int colc = bn + ((w >> 1)*4 + j2)*16 + mm;
    asv[j2] = asrc[colc];
    adv[j2] = adst[colc];
  }

  f32x4 acc[4][4];
#pragma unroll
  for (int i = 0; i < 4; i++)
#pragma unroll
    for (int j = 0; j < 4; j++)
#pragma unroll
      for (int r = 0; r < 4; r++) acc[i][j][r] = 0.f;

  const int niter = K2 >> 6;
  for (int it = 0; it < niter; it++){
    __syncthreads();
#pragma unroll
    for (int jj = 0; jj < 4; jj++){
      int fb = w*4 + jj;
      __builtin_amdgcn_global_load_lds(
          (const gbl_u32*)gA[jj], (lds_u32*)(As + fb*64), 16, 0, 0);
      __builtin_amdgcn_global_load_lds(
          (const gbl_u32*)gB[jj], (lds_u32*)(Bs + fb*64), 16, 0, 0);
      gA[jj] += 64;
      gB[jj] += 64;
    }
    __syncthreads();
#pragma unroll
    for (int s = 0; s < 2; s++){
      bf16x8 af[4], bfr[4];
#pragma unroll
      for (int i2 = 0; i2 < 4; i2++){
        int fbA = ((((w & 1)*4) + i2) << 1) | s;
        af[i2]  = *(bf16x8*)&As[fbA*64 + lane];
        int fbB = ((((w >> 1)*4) + i2) << 1) | s;
        bfr[i2] = *(bf16x8*)&Bs[fbB*64 + lane];
      }
#pragma unroll
      for (int i2 = 0; i2 < 4; i2++)
#pragma unroll
        for (int j2 = 0; j2 < 4; j2++)
          acc[i2][j2] = __builtin_amdgcn_mfma_f32_16x16x32_bf16(
              af[i2], bfr[j2], acc[i2][j2], 0, 0, 0);
    }
  }

  const int hd = (H == 4) ? (bn >> 7) : 0;
#pragma unroll
  for (int i2 = 0; i2 < 4; i2++){
    int rbase = bm + ((w & 1)*4 + i2)*16 + q*4;
#pragma unroll
    for (int r = 0; r < 4; r++){
      int row = rbase + r;
      // Hb store (bf16) for this row across the lane's 4 cols
      float ps = 0.f, pd = 0.f;
#pragma unroll
      for (int j2 = 0; j2 < 4; j2++){
        float v = acc[i2][j2][r];
        int colc = bn + ((w >> 1)*4 + j2)*16 + mm;
        if (row < M) Hb[(size_t)row*512 + colc] = (__bf16)v;
        ps += v * asv[j2];
        pd += v * adv[j2];
      }
      // reduce over the 16 mm-lanes of this quarter
#pragma unroll
      for (int off = 1; off < 16; off <<= 1){
        ps += __shfl_xor(ps, off);
        pd += __shfl_xor(pd, off);
      }
      if (mm == 0 && row < M){
        atomicAdd(&al_s[(size_t)row*H + hd], ps);
        atomicAdd(&al_d[(size_t)row*H + hd], pd);
      }
    }
  }
}

// ========== per-dst softmax: one WAVE per node, shuffle-only ================
// alphaE layout: [H][Etot] (transposed) so per-head slices are contiguous.
template<int H>
__global__ __launch_bounds__(64) void alpha_kernel(
    const float* __restrict__ al_s, const float* __restrict__ al_d,
    const int* __restrict__ rowptr, const int* __restrict__ col,
    float* __restrict__ alphaE, float* __restrict__ denom, int Etot){
  int d = blockIdx.x;
  int lane = threadIdx.x;              // 0..63
  int start = rowptr[d], end = rowptr[d + 1];

  float ald[H];
#pragma unroll
  for (int h = 0; h < H; h++) ald[h] = al_d[(size_t)d*H + h];

  float mx[H];
#pragma unroll
  for (int h = 0; h < H; h++) mx[h] = -1e30f;
  for (int e = start + lane; e < end; e += 64){
    int s = col[e];
#pragma unroll
    for (int h = 0; h < H; h++){
      float v = al_s[(size_t)s*H + h] + ald[h];
      v = (v > 0.f) ? v : NSLOPE * v;
      mx[h] = fmaxf(mx[h], v);
    }
  }
#pragma unroll
  for (int h = 0; h < H; h++)
#pragma unroll
    for (int off = 32; off > 0; off >>= 1)
      mx[h] = fmaxf(mx[h], __shfl_xor(mx[h], off));

  float sm[H] = {};
  for (int e = start + lane; e < end; e += 64){
    int s = col[e];
#pragma unroll
    for (int h = 0; h < H; h++){
      float v = al_s[(size_t)s*H + h] + ald[h];
      v = (v > 0.f) ? v : NSLOPE * v;
      float ev = __expf(v - mx[h]);
      alphaE[(size_t)h*Etot + e] = ev;
      sm[h] += ev;
    }
  }
#pragma unroll
  for (int h = 0; h < H; h++)
#pragma unroll
    for (int off = 32; off > 0; off >>= 1)
      sm[h] += __shfl_xor(sm[h], off);
  if (lane == 0){
#pragma unroll
    for (int h = 0; h < H; h++) denom[(size_t)d*H + h] = sm[h];
  }
}

// ====== channel-sliced weighted gather, XCD-pinned ==========================
// grid g: x = g&7 -> XCD; slice s = x>>1 (128 ch), half = x&1.
// per-slice working set N*256B = 2.56 MB fits one XCD's 4 MB L2.
// MODE 0: fp32 out, no ReLU.  MODE 1: ReLU + bf16 hi/lo into feat2 row.
template<int H, int MODE>
__global__ __launch_bounds__(64) void aggregate_slice(
    const __bf16* __restrict__ Hb, const float* __restrict__ alphaE,
    const float* __restrict__ denom, const int* __restrict__ rowptr,
    const int* __restrict__ col, const float* __restrict__ bias,
    float* __restrict__ outF, __bf16* __restrict__ fhi,
    __bf16* __restrict__ flo, int fstride, int nidx, int N, int Etot){
  int g = blockIdx.x;
  int x = g & 7, idx = g >> 3;
  int s = x >> 1, half = x & 1;
  int d = half * nidx + idx;
  if (d >= N) return;
  int lane = threadIdx.x;
  int start = rowptr[d], end = rowptr[d + 1];
  const int hh = (H == 1) ? 0 : s;
  const float* __restrict__ aE = alphaE + (size_t)hh*Etot;
  const bf16x2* __restrict__ Hb2 = (const bf16x2*)Hb;   // row = 256 units
  const size_t coff = s*64 + lane;

  __shared__ int   src_s[64];
  __shared__ float a_s[64];

  float ax0=0.f, ay0=0.f, ax1=0.f, ay1=0.f;
  float ax2=0.f, ay2=0.f, ax3=0.f, ay3=0.f;

  for (int c0 = start; c0 < end; c0 += 64){
    int cnt = min(64, end - c0);
    if (lane < cnt){
      int e = c0 + lane;
      src_s[lane] = col[e];
      a_s[lane]   = aE[e];
    }
    __syncthreads();
    int i = 0;
    for (; i + 4 <= cnt; i += 4){
      int s0 = src_s[i],   s1 = src_s[i+1];
      int s2 = src_s[i+2], s3 = src_s[i+3];
      float e0 = a_s[i],   e1 = a_s[i+1];
      float e2 = a_s[i+2], e3 = a_s[i+3];
      bf16x2 v0 = Hb2[(size_t)s0*256 + coff];
      bf16x2 v1 = Hb2[(size_t)s1*256 + coff];
      bf16x2 v2 = Hb2[(size_t)s2*256 + coff];
      bf16x2 v3 = Hb2[(size_t)s3*256 + coff];
      ax0 += e0*(float)v0[0]; ay0 += e0*(float)v0[1];
      ax1 += e1*(float)v1[0]; ay1 += e1*(float)v1[1];
      ax2 += e2*(float)v2[0]; ay2 += e2*(float)v2[1];
      ax3 += e3*(float)v3[0]; ay3 += e3*(float)v3[1];
    }
    for (; i < cnt; i++){
      int s0 = src_s[i];
      float e0 = a_s[i];
      bf16x2 v0 = Hb2[(size_t)s0*256 + coff];
      ax0 += e0*(float)v0[0]; ay0 += e0*(float)v0[1];
    }
    __syncthreads();
  }

  float accx = (ax0 + ax1) + (ax2 + ax3);
  float accy = (ay0 + ay1) + (ay2 + ay3);
  float invd = 1.f / denom[(size_t)d*H + hh];
  int c = s*128 + lane*2;
  float2 bv = *(const float2*)(bias + c);
  float r0 = accx * invd + bv.x;
  float r1 = accy * invd + bv.y;
  if (MODE == 1){
    r0 = fmaxf(r0, 0.f); r1 = fmaxf(r1, 0.f);
    __bf16 h0 = (__bf16)r0, h1 = (__bf16)r1;
    bf16x2 hv; hv[0] = h0; hv[1] = h1;
    bf16x2 lv; lv[0] = (__bf16)(r0 - (float)h0); lv[1] = (__bf16)(r1 - (float)h1);
    *(bf16x2*)(fhi + (size_t)d*fstride + c) = hv;
    *(bf16x2*)(flo + (size_t)d*fstride + c) = lv;
  } else {
    *(float2*)(outF + (size_t)d*512 + c) = make_float2(r0, r1);
  }
}

// =========================== launch =========================================
extern "C" void kernel_launch(void* const* d_in, const int* in_sizes, int n_in,
                              void* d_out, int out_size, void* d_ws, size_t ws_size,
                              hipStream_t stream){
  const float* x   = (const float*)d_in[0];
  const int*   ei  = (const int*)  d_in[1];
  const float* W1  = (const float*)d_in[2];
  const float* as1 = (const float*)d_in[3];
  const float* ad1 = (const float*)d_in[4];
  const float* b1  = (const float*)d_in[5];
  const float* W2  = (const float*)d_in[6];
  const float* as2 = (const float*)d_in[7];
  const float* ad2 = (const float*)d_in[8];
  const float* b2  = (const float*)d_in[9];
  const float* W3  = (const float*)d_in[10];
  const float* as3 = (const float*)d_in[11];
  const float* ad3 = (const float*)d_in[12];
  const float* b3  = (const float*)d_in[13];
  float* out = (float*)d_out;

  const int N = in_sizes[0] / 128;   // 10000
  const int E = in_sizes[1] / 2;     // 320000
  const int F = 512;
  const int Etot = E + N;
  const int nidx = (N + 1) / 2;

  // workspace carve-up
  __bf16* feat2  = (__bf16*)d_ws;                     // N*1024 bf16 (hi|lo)
  float*  al_s   = (float*)(feat2 + (size_t)N*1024);  // N*4
  float*  al_d   = al_s + (size_t)N*4;                // N*4
  float*  alphaE = al_d + (size_t)N*4;                // [H][E+N] = (E+N)*4
  float*  denom  = alphaE + (size_t)Etot*4;           // N*4
  int*    cnt    = (int*)(denom + (size_t)N*4);       // N
  int*    rowptr = cnt + N;                           // N+1
  int*    cursor = rowptr + N + 1;                    // N
  int*    col    = cursor + N;                        // E+N
  uintptr_t p  = (uintptr_t)(col + Etot);
  p = (p + 15) & ~(uintptr_t)15;
  __bf16* B2t = (__bf16*)p;                           // 512*1024 bf16
  __bf16* Hb  = B2t + 512*1024;                       // N*512 bf16 (gather)
  // X2 (N*256 bf16 = 5.12 MB) aliases alphaE region (5.28 MB): consumed by
  // the layer-1 gemm BEFORE alpha_kernel first writes alphaE.
  __bf16* X2 = (__bf16*)alphaE;

  // CSR by destination
  init_cnt_kernel<<<(N+255)/256, 256, 0, stream>>>(cnt, N);
  hist_kernel<<<(E+255)/256, 256, 0, stream>>>(ei, E, cnt);
  scan_kernel<<<1, 1024, 0, stream>>>(cnt, rowptr, cursor, N);
  fill_kernel<<<(E+N+255)/256, 256, 0, stream>>>(ei, E, N, cursor, col);

  const int ggrid = ((N + 127)/128) * (F/128);   // 79 * 4 = 316 blocks
  const int agrid = nidx * 8;

  // ---- layer 1: x[N,128] @ W1[128,512]  (K2 = 256) ----
  split_kernel<<<(N*128/4 + 255)/256, 256, 0, stream>>>(x, X2, N*128);
  wsplit_kernel<<<dim3(128/32, F/32), 256, 0, stream>>>(W1, B2t, 128, F, al_s, al_d, N*4);
  gemm_mfma<4><<<ggrid, 256, 0, stream>>>(X2, B2t, Hb, as1, ad1, al_s, al_d, N, F, 256);
  alpha_kernel<4><<<N, 64, 0, stream>>>(al_s, al_d, rowptr, col, alphaE, denom, Etot);
  aggregate_slice<4,1><<<agrid, 64, 0, stream>>>(Hb, alphaE, denom, rowptr, col, b1,
      (float*)nullptr, feat2, feat2 + 512, 1024, nidx, N, Etot);

  // ---- layer 2: feat[N,512] @ W2[512,512]  (K2 = 1024) ----
  wsplit_kernel<<<dim3(F/32, F/32), 256, 0, stream>>>(W2, B2t, F, F, al_s, al_d, N*4);
  gemm_mfma<4><<<ggrid, 256, 0, stream>>>(feat2, B2t, Hb, as2, ad2, al_s, al_d, N, F, 1024);
  alpha_kernel<4><<<N, 64, 0, stream>>>(al_s, al_d, rowptr, col, alphaE, denom, Etot);
  aggregate_slice<4,1><<<agrid, 64, 0, stream>>>(Hb, alphaE, denom, rowptr, col, b2,
      (float*)nullptr, feat2, feat2 + 512, 1024, nidx, N, Etot);

  // ---- layer 3: feat[N,512] @ W3[512,512], heads=1  (K2 = 1024) ----
  wsplit_kernel<<<dim3(F/32, F/32), 256, 0, stream>>>(W3, B2t, F, F, al_s, al_d, N);
  gemm_mfma<1><<<ggrid, 256, 0, stream>>>(feat2, B2t, Hb, as3, ad3, al_s, al_d, N, F, 1024);
  alpha_kernel<1><<<N, 64, 0, stream>>>(al_s, al_d, rowptr, col, alphaE, denom, Etot);
  aggregate_slice<1,0><<<agrid, 64, 0, stream>>>(Hb, alphaE, denom, rowptr, col, b3,
      out, (__bf16*)nullptr, (__bf16*)nullptr, 0, nidx, N, Etot);
}

// Round 11
// 359.949 us; speedup vs baseline: 1.2129x; 1.0287x over previous
//
#include <hip/hip_runtime.h>

#define NSLOPE 0.2f

typedef __bf16 bf16x8 __attribute__((ext_vector_type(8)));
typedef __bf16 bf16x4 __attribute__((ext_vector_type(4)));
typedef __bf16 bf16x2 __attribute__((ext_vector_type(2)));
typedef float  f32x4  __attribute__((ext_vector_type(4)));

typedef uint32_t __attribute__((address_space(1))) gbl_u32;
typedef uint32_t __attribute__((address_space(3))) lds_u32;

// ======================= CSR build (per-launch; ws is re-poisoned) ==========
__global__ void init_cnt_kernel(int* cnt, int n){
  int i = blockIdx.x*blockDim.x + threadIdx.x;
  if (i < n) cnt[i] = 1;                       // count the self-loop up front
}

__global__ void hist_kernel(const int* __restrict__ ei, int E, int* cnt){
  int e = blockIdx.x*blockDim.x + threadIdx.x;
  if (e < E) atomicAdd(&cnt[ei[E + e]], 1);    // dst row of edge_index
}

// single-block scan, wave-shuffle based
__global__ void scan_kernel(const int* __restrict__ cnt, int* __restrict__ rowptr,
                            int* __restrict__ cursor, int n){
  __shared__ int wsum[16];
  __shared__ int carry, chunk_total;
  int t = threadIdx.x, lane = t & 63, wid = t >> 6;
  if (t == 0) carry = 0;
  __syncthreads();
  for (int base = 0; base < n; base += 1024){
    int idx = base + t;
    int v = (idx < n) ? cnt[idx] : 0;
    int inc = v;
#pragma unroll
    for (int off = 1; off < 64; off <<= 1){
      int u = __shfl_up(inc, off);
      if (lane >= off) inc += u;
    }
    if (lane == 63) wsum[wid] = inc;
    __syncthreads();
    if (t == 0){
      int s = 0;
#pragma unroll
      for (int i = 0; i < 16; i++){ int x = wsum[i]; wsum[i] = s; s += x; }
      chunk_total = s;
    }
    __syncthreads();
    int excl = carry + wsum[wid] + inc - v;
    if (idx < n){ rowptr[idx] = excl; cursor[idx] = excl; }
    __syncthreads();
    if (t == 0) carry += chunk_total;
    __syncthreads();
  }
  if (t == 0) rowptr[n] = carry;
}

__global__ void fill_kernel(const int* __restrict__ ei, int E, int n,
                            int* cursor, int* __restrict__ col){
  int i = blockIdx.x*blockDim.x + threadIdx.x;
  if (i < E){
    int s = ei[i], d = ei[E + i];
    int slot = atomicAdd(&cursor[d], 1);
    col[slot] = s;
  } else if (i < E + n){
    int v = i - E;                             // self loop (v -> v)
    int slot = atomicAdd(&cursor[v], 1);
    col[slot] = v;
  }
}

// ===== W [K][Nc] fp32 -> B2t [Nc][2K] bf16: hi at [n][k], lo at [n][K+k] ====
__global__ __launch_bounds__(256) void wsplit_kernel(
    const float* __restrict__ W, __bf16* __restrict__ B2t, int K, int Nc){
  __shared__ float hi_s[32][33], lo_s[32][33];
  int tx = threadIdx.x & 31, ty = threadIdx.x >> 5;   // 32 x 8
  int k0 = blockIdx.x * 32, n0 = blockIdx.y * 32;
#pragma unroll
  for (int i = 0; i < 4; i++){
    int r = ty + i*8;
    float v = W[(size_t)(k0 + r)*Nc + n0 + tx];
    float h = (float)(__bf16)v;
    hi_s[r][tx] = h;
    lo_s[r][tx] = v - h;
  }
  __syncthreads();
  int K2 = 2*K;
#pragma unroll
  for (int i = 0; i < 4; i++){
    int n = ty + i*8;
    B2t[(size_t)(n0 + n)*K2 + k0 + tx]     = (__bf16)hi_s[tx][n];
    B2t[(size_t)(n0 + n)*K2 + K + k0 + tx] = (__bf16)lo_s[tx][n];
  }
}

// ===== x [N][128] fp32 -> X2 [N][256] bf16 (hi cols 0..127, lo 128..255) ====
__global__ __launch_bounds__(256) void split_kernel(
    const float* __restrict__ X, __bf16* __restrict__ X2, int total){
  int i = (blockIdx.x*256 + threadIdx.x)*4;
  if (i < total){
    int n = i >> 7, c = i & 127;
    float4 v = *(const float4*)(X + i);
    float f[4] = {v.x, v.y, v.z, v.w};
    bf16x4 h, l;
#pragma unroll
    for (int u = 0; u < 4; u++){
      __bf16 hh = (__bf16)f[u];
      h[u] = hh;
      l[u] = (__bf16)(f[u] - (float)hh);
    }
    *(bf16x4*)(X2 + (size_t)n*256 + c)       = h;
    *(bf16x4*)(X2 + (size_t)n*256 + 128 + c) = l;
  }
}

// ========== bf16 MFMA GEMM over K2=2K (hi|lo fold), bf16 output =============
// m97 structure: 128x128 tile, 256 thr, single LDS buffer, global_load_lds
// width=16, 2 barriers/iter, fragment-major LDS (conflict-free both ways).
// Epilogue: plain bf16 Hb stores (no reductions — see R9 post-mortem:
// fused dot-product epilogue cost ~20 us/dispatch).
__global__ __launch_bounds__(256) void gemm_mfma(
    const __bf16* __restrict__ A2, const __bf16* __restrict__ B2t,
    __bf16* __restrict__ Hb, int M, int Nc, int K2){
  __shared__ uint4 As[1024];   // 16 fb x 64 lanes, 16 KiB
  __shared__ uint4 Bs[1024];   // 16 KiB
  int t = threadIdx.x, w = t >> 6, lane = t & 63;
  int mm = lane & 15, q = lane >> 4;
  int blk = blockIdx.x;
  int bm = (blk >> 2) * 128;          // Nc/128 == 4 always here
  int bn = (blk & 3) * 128;

  const __bf16* gA[4];
  const __bf16* gB[4];
#pragma unroll
  for (int jj = 0; jj < 4; jj++){
    int fb = w*4 + jj;
    int i = fb >> 1, s = fb & 1;
    int rowA = bm + i*16 + mm; rowA = (rowA < M) ? rowA : (M - 1);
    gA[jj] = A2 + (size_t)rowA*K2 + s*32 + q*8;
    int rowB = bn + i*16 + mm;
    gB[jj] = B2t + (size_t)rowB*K2 + s*32 + q*8;
  }

  f32x4 acc[4][4];
#pragma unroll
  for (int i = 0; i < 4; i++)
#pragma unroll
    for (int j = 0; j < 4; j++)
#pragma unroll
      for (int r = 0; r < 4; r++) acc[i][j][r] = 0.f;

  const int niter = K2 >> 6;
  for (int it = 0; it < niter; it++){
    __syncthreads();
#pragma unroll
    for (int jj = 0; jj < 4; jj++){
      int fb = w*4 + jj;
      __builtin_amdgcn_global_load_lds(
          (const gbl_u32*)gA[jj], (lds_u32*)(As + fb*64), 16, 0, 0);
      __builtin_amdgcn_global_load_lds(
          (const gbl_u32*)gB[jj], (lds_u32*)(Bs + fb*64), 16, 0, 0);
      gA[jj] += 64;
      gB[jj] += 64;
    }
    __syncthreads();
#pragma unroll
    for (int s = 0; s < 2; s++){
      bf16x8 af[4], bfr[4];
#pragma unroll
      for (int i2 = 0; i2 < 4; i2++){
        int fbA = ((((w & 1)*4) + i2) << 1) | s;
        af[i2]  = *(bf16x8*)&As[fbA*64 + lane];
        int fbB = ((((w >> 1)*4) + i2) << 1) | s;
        bfr[i2] = *(bf16x8*)&Bs[fbB*64 + lane];
      }
#pragma unroll
      for (int i2 = 0; i2 < 4; i2++)
#pragma unroll
        for (int j2 = 0; j2 < 4; j2++)
          acc[i2][j2] = __builtin_amdgcn_mfma_f32_16x16x32_bf16(
              af[i2], bfr[j2], acc[i2][j2], 0, 0, 0);
    }
  }

#pragma unroll
  for (int i2 = 0; i2 < 4; i2++){
    int rbase = bm + ((w & 1)*4 + i2)*16 + q*4;
#pragma unroll
    for (int j2 = 0; j2 < 4; j2++){
      int colc = bn + ((w >> 1)*4 + j2)*16 + mm;
#pragma unroll
      for (int r = 0; r < 4; r++){
        int row = rbase + r;
        if (row < M) Hb[(size_t)row*512 + colc] = (__bf16)acc[i2][j2][r];
      }
    }
  }
}

// ===== attention coefficients from Hb (bf16): one wave per node =============
// lane owns 8 contiguous channels (bf16x8 = 16 B); head = lane>>4 for H=4.
template<int H>
__global__ __launch_bounds__(256) void attn_bf16(
    const __bf16* __restrict__ Hb, const float* __restrict__ asrc,
    const float* __restrict__ adst, float* __restrict__ al_s,
    float* __restrict__ al_d, int N){
  int lane = threadIdx.x & 63, wv = threadIdx.x >> 6;
  int n = blockIdx.x*4 + wv;
  if (n >= N) return;
  float asv[8], adv[8];
#pragma unroll
  for (int u = 0; u < 8; u++){
    asv[u] = asrc[lane*8 + u];
    adv[u] = adst[lane*8 + u];
  }
  bf16x8 v = *(const bf16x8*)(Hb + (size_t)n*512 + lane*8);
  float ss = 0.f, sd = 0.f;
#pragma unroll
  for (int u = 0; u < 8; u++){
    float f = (float)v[u];
    ss += f * asv[u];
    sd += f * adv[u];
  }
  const int red = (H == 4) ? 16 : 64;    // lanes per head group
#pragma unroll
  for (int off = 1; off < 64; off <<= 1){
    if (off < red){
      ss += __shfl_xor(ss, off);
      sd += __shfl_xor(sd, off);
    }
  }
  if ((lane & (red - 1)) == 0){
    int h = (H == 4) ? (lane >> 4) : 0;
    al_s[(size_t)n*H + h] = ss;
    al_d[(size_t)n*H + h] = sd;
  }
}

// ========== per-dst softmax: one WAVE per node, shuffle-only ================
// alphaE layout: [H][Etot] (transposed) so per-head slices are contiguous.
template<int H>
__global__ __launch_bounds__(64) void alpha_kernel(
    const float* __restrict__ al_s, const float* __restrict__ al_d,
    const int* __restrict__ rowptr, const int* __restrict__ col,
    float* __restrict__ alphaE, float* __restrict__ denom, int Etot){
  int d = blockIdx.x;
  int lane = threadIdx.x;              // 0..63
  int start = rowptr[d], end = rowptr[d + 1];

  float ald[H];
#pragma unroll
  for (int h = 0; h < H; h++) ald[h] = al_d[(size_t)d*H + h];

  float mx[H];
#pragma unroll
  for (int h = 0; h < H; h++) mx[h] = -1e30f;
  for (int e = start + lane; e < end; e += 64){
    int s = col[e];
#pragma unroll
    for (int h = 0; h < H; h++){
      float v = al_s[(size_t)s*H + h] + ald[h];
      v = (v > 0.f) ? v : NSLOPE * v;
      mx[h] = fmaxf(mx[h], v);
    }
  }
#pragma unroll
  for (int h = 0; h < H; h++)
#pragma unroll
    for (int off = 32; off > 0; off >>= 1)
      mx[h] = fmaxf(mx[h], __shfl_xor(mx[h], off));

  float sm[H] = {};
  for (int e = start + lane; e < end; e += 64){
    int s = col[e];
#pragma unroll
    for (int h = 0; h < H; h++){
      float v = al_s[(size_t)s*H + h] + ald[h];
      v = (v > 0.f) ? v : NSLOPE * v;
      float ev = __expf(v - mx[h]);
      alphaE[(size_t)h*Etot + e] = ev;
      sm[h] += ev;
    }
  }
#pragma unroll
  for (int h = 0; h < H; h++)
#pragma unroll
    for (int off = 32; off > 0; off >>= 1)
      sm[h] += __shfl_xor(sm[h], off);
  if (lane == 0){
#pragma unroll
    for (int h = 0; h < H; h++) denom[(size_t)d*H + h] = sm[h];
  }
}

// ====== channel-sliced weighted gather, XCD-pinned ==========================
// grid g: x = g&7 -> XCD; slice s = x>>1 (128 ch), half = x&1.
// per-slice working set N*256B = 2.56 MB fits one XCD's 4 MB L2.
// MODE 0: fp32 out, no ReLU.  MODE 1: ReLU + bf16 hi/lo into feat2 row.
template<int H, int MODE>
__global__ __launch_bounds__(64) void aggregate_slice(
    const __bf16* __restrict__ Hb, const float* __restrict__ alphaE,
    const float* __restrict__ denom, const int* __restrict__ rowptr,
    const int* __restrict__ col, const float* __restrict__ bias,
    float* __restrict__ outF, __bf16* __restrict__ fhi,
    __bf16* __restrict__ flo, int fstride, int nidx, int N, int Etot){
  int g = blockIdx.x;
  int x = g & 7, idx = g >> 3;
  int s = x >> 1, half = x & 1;
  int d = half * nidx + idx;
  if (d >= N) return;
  int lane = threadIdx.x;
  int start = rowptr[d], end = rowptr[d + 1];
  const int hh = (H == 1) ? 0 : s;
  const float* __restrict__ aE = alphaE + (size_t)hh*Etot;
  const bf16x2* __restrict__ Hb2 = (const bf16x2*)Hb;   // row = 256 units
  const size_t coff = s*64 + lane;

  __shared__ int   src_s[64];
  __shared__ float a_s[64];

  float ax0=0.f, ay0=0.f, ax1=0.f, ay1=0.f;
  float ax2=0.f, ay2=0.f, ax3=0.f, ay3=0.f;

  for (int c0 = start; c0 < end; c0 += 64){
    int cnt = min(64, end - c0);
    if (lane < cnt){
      int e = c0 + lane;
      src_s[lane] = col[e];
      a_s[lane]   = aE[e];
    }
    __syncthreads();
    int i = 0;
    for (; i + 4 <= cnt; i += 4){
      int s0 = src_s[i],   s1 = src_s[i+1];
      int s2 = src_s[i+2], s3 = src_s[i+3];
      float e0 = a_s[i],   e1 = a_s[i+1];
      float e2 = a_s[i+2], e3 = a_s[i+3];
      bf16x2 v0 = Hb2[(size_t)s0*256 + coff];
      bf16x2 v1 = Hb2[(size_t)s1*256 + coff];
      bf16x2 v2 = Hb2[(size_t)s2*256 + coff];
      bf16x2 v3 = Hb2[(size_t)s3*256 + coff];
      ax0 += e0*(float)v0[0]; ay0 += e0*(float)v0[1];
      ax1 += e1*(float)v1[0]; ay1 += e1*(float)v1[1];
      ax2 += e2*(float)v2[0]; ay2 += e2*(float)v2[1];
      ax3 += e3*(float)v3[0]; ay3 += e3*(float)v3[1];
    }
    for (; i < cnt; i++){
      int s0 = src_s[i];
      float e0 = a_s[i];
      bf16x2 v0 = Hb2[(size_t)s0*256 + coff];
      ax0 += e0*(float)v0[0]; ay0 += e0*(float)v0[1];
    }
    __syncthreads();
  }

  float accx = (ax0 + ax1) + (ax2 + ax3);
  float accy = (ay0 + ay1) + (ay2 + ay3);
  float invd = 1.f / denom[(size_t)d*H + hh];
  int c = s*128 + lane*2;
  float2 bv = *(const float2*)(bias + c);
  float r0 = accx * invd + bv.x;
  float r1 = accy * invd + bv.y;
  if (MODE == 1){
    r0 = fmaxf(r0, 0.f); r1 = fmaxf(r1, 0.f);
    __bf16 h0 = (__bf16)r0, h1 = (__bf16)r1;
    bf16x2 hv; hv[0] = h0; hv[1] = h1;
    bf16x2 lv; lv[0] = (__bf16)(r0 - (float)h0); lv[1] = (__bf16)(r1 - (float)h1);
    *(bf16x2*)(fhi + (size_t)d*fstride + c) = hv;
    *(bf16x2*)(flo + (size_t)d*fstride + c) = lv;
  } else {
    *(float2*)(outF + (size_t)d*512 + c) = make_float2(r0, r1);
  }
}

// =========================== launch =========================================
extern "C" void kernel_launch(void* const* d_in, const int* in_sizes, int n_in,
                              void* d_out, int out_size, void* d_ws, size_t ws_size,
                              hipStream_t stream){
  const float* x   = (const float*)d_in[0];
  const int*   ei  = (const int*)  d_in[1];
  const float* W1  = (const float*)d_in[2];
  const float* as1 = (const float*)d_in[3];
  const float* ad1 = (const float*)d_in[4];
  const float* b1  = (const float*)d_in[5];
  const float* W2  = (const float*)d_in[6];
  const float* as2 = (const float*)d_in[7];
  const float* ad2 = (const float*)d_in[8];
  const float* b2  = (const float*)d_in[9];
  const float* W3  = (const float*)d_in[10];
  const float* as3 = (const float*)d_in[11];
  const float* ad3 = (const float*)d_in[12];
  const float* b3  = (const float*)d_in[13];
  float* out = (float*)d_out;

  const int N = in_sizes[0] / 128;   // 10000
  const int E = in_sizes[1] / 2;     // 320000
  const int F = 512;
  const int Etot = E + N;
  const int nidx = (N + 1) / 2;

  // workspace carve-up
  __bf16* feat2  = (__bf16*)d_ws;                     // N*1024 bf16 (hi|lo)
  float*  al_s   = (float*)(feat2 + (size_t)N*1024);  // N*4
  float*  al_d   = al_s + (size_t)N*4;                // N*4
  float*  alphaE = al_d + (size_t)N*4;                // [H][E+N] = (E+N)*4
  float*  denom  = alphaE + (size_t)Etot*4;           // N*4
  int*    cnt    = (int*)(denom + (size_t)N*4);       // N
  int*    rowptr = cnt + N;                           // N+1
  int*    cursor = rowptr + N + 1;                    // N
  int*    col    = cursor + N;                        // E+N
  uintptr_t p  = (uintptr_t)(col + Etot);
  p = (p + 15) & ~(uintptr_t)15;
  __bf16* B2t = (__bf16*)p;                           // 512*1024 bf16
  __bf16* Hb  = B2t + 512*1024;                       // N*512 bf16 (gather)
  // X2 (N*256 bf16 = 5.12 MB) aliases alphaE region (5.28 MB): consumed by
  // the layer-1 gemm BEFORE alpha_kernel first writes alphaE.
  __bf16* X2 = (__bf16*)alphaE;

  // CSR by destination
  init_cnt_kernel<<<(N+255)/256, 256, 0, stream>>>(cnt, N);
  hist_kernel<<<(E+255)/256, 256, 0, stream>>>(ei, E, cnt);
  scan_kernel<<<1, 1024, 0, stream>>>(cnt, rowptr, cursor, N);
  fill_kernel<<<(E+N+255)/256, 256, 0, stream>>>(ei, E, N, cursor, col);

  const int ggrid = ((N + 127)/128) * (F/128);   // 79 * 4 = 316 blocks
  const int agrid = nidx * 8;
  const int ngrid = (N + 3)/4;

  // ---- layer 1: x[N,128] @ W1[128,512]  (K2 = 256) ----
  split_kernel<<<(N*128/4 + 255)/256, 256, 0, stream>>>(x, X2, N*128);
  wsplit_kernel<<<dim3(128/32, F/32), 256, 0, stream>>>(W1, B2t, 128, F);
  gemm_mfma<<<ggrid, 256, 0, stream>>>(X2, B2t, Hb, N, F, 256);
  attn_bf16<4><<<ngrid, 256, 0, stream>>>(Hb, as1, ad1, al_s, al_d, N);
  alpha_kernel<4><<<N, 64, 0, stream>>>(al_s, al_d, rowptr, col, alphaE, denom, Etot);
  aggregate_slice<4,1><<<agrid, 64, 0, stream>>>(Hb, alphaE, denom, rowptr, col, b1,
      (float*)nullptr, feat2, feat2 + 512, 1024, nidx, N, Etot);

  // ---- layer 2: feat[N,512] @ W2[512,512]  (K2 = 1024) ----
  wsplit_kernel<<<dim3(F/32, F/32), 256, 0, stream>>>(W2, B2t, F, F);
  gemm_mfma<<<ggrid, 256, 0, stream>>>(feat2, B2t, Hb, N, F, 1024);
  attn_bf16<4><<<ngrid, 256, 0, stream>>>(Hb, as2, ad2, al_s, al_d, N);
  alpha_kernel<4><<<N, 64, 0, stream>>>(al_s, al_d, rowptr, col, alphaE, denom, Etot);
  aggregate_slice<4,1><<<agrid, 64, 0, stream>>>(Hb, alphaE, denom, rowptr, col, b2,
      (float*)nullptr, feat2, feat2 + 512, 1024, nidx, N, Etot);

  // ---- layer 3: feat[N,512] @ W3[512,512], heads=1  (K2 = 1024) ----
  wsplit_kernel<<<dim3(F/32, F/32), 256, 0, stream>>>(W3, B2t, F, F);
  gemm_mfma<<<ggrid, 256, 0, stream>>>(feat2, B2t, Hb, N, F, 1024);
  attn_bf16<1><<<ngrid, 256, 0, stream>>>(Hb, as3, ad3, al_s, al_d, N);
  alpha_kernel<1><<<N, 64, 0, stream>>>(al_s, al_d, rowptr, col, alphaE, denom, Etot);
  aggregate_slice<1,0><<<agrid, 64, 0, stream>>>(Hb, alphaE, denom, rowptr, col, b3,
      out, (__bf16*)nullptr, (__bf16*)nullptr, 0, nidx, N, Etot);
}

// Round 12
// 358.290 us; speedup vs baseline: 1.2185x; 1.0046x over previous
//
#include <hip/hip_runtime.h>

#define NSLOPE 0.2f

typedef __bf16 bf16x8 __attribute__((ext_vector_type(8)));
typedef __bf16 bf16x4 __attribute__((ext_vector_type(4)));
typedef __bf16 bf16x2 __attribute__((ext_vector_type(2)));
typedef float  f32x4  __attribute__((ext_vector_type(4)));

typedef uint32_t __attribute__((address_space(1))) gbl_u32;
typedef uint32_t __attribute__((address_space(3))) lds_u32;

// ======================= CSR build (per-launch; ws is re-poisoned) ==========
__global__ void init_cnt_kernel(int* cnt, int n){
  int i = blockIdx.x*blockDim.x + threadIdx.x;
  if (i < n) cnt[i] = 1;                       // count the self-loop up front
}

__global__ void hist_kernel(const int* __restrict__ ei, int E, int* cnt){
  int e = blockIdx.x*blockDim.x + threadIdx.x;
  if (e < E) atomicAdd(&cnt[ei[E + e]], 1);    // dst row of edge_index
}

// single-block scan, wave-shuffle based
__global__ void scan_kernel(const int* __restrict__ cnt, int* __restrict__ rowptr,
                            int* __restrict__ cursor, int n){
  __shared__ int wsum[16];
  __shared__ int carry, chunk_total;
  int t = threadIdx.x, lane = t & 63, wid = t >> 6;
  if (t == 0) carry = 0;
  __syncthreads();
  for (int base = 0; base < n; base += 1024){
    int idx = base + t;
    int v = (idx < n) ? cnt[idx] : 0;
    int inc = v;
#pragma unroll
    for (int off = 1; off < 64; off <<= 1){
      int u = __shfl_up(inc, off);
      if (lane >= off) inc += u;
    }
    if (lane == 63) wsum[wid] = inc;
    __syncthreads();
    if (t == 0){
      int s = 0;
#pragma unroll
      for (int i = 0; i < 16; i++){ int x = wsum[i]; wsum[i] = s; s += x; }
      chunk_total = s;
    }
    __syncthreads();
    int excl = carry + wsum[wid] + inc - v;
    if (idx < n){ rowptr[idx] = excl; cursor[idx] = excl; }
    __syncthreads();
    if (t == 0) carry += chunk_total;
    __syncthreads();
  }
  if (t == 0) rowptr[n] = carry;
}

__global__ void fill_kernel(const int* __restrict__ ei, int E, int n,
                            int* cursor, int* __restrict__ col){
  int i = blockIdx.x*blockDim.x + threadIdx.x;
  if (i < E){
    int s = ei[i], d = ei[E + i];
    int slot = atomicAdd(&cursor[d], 1);
    col[slot] = s;
  } else if (i < E + n){
    int v = i - E;                             // self loop (v -> v)
    int slot = atomicAdd(&cursor[v], 1);
    col[slot] = v;
  }
}

// ===== W [K][Nc] fp32 -> B2t [Nc][2K] bf16: hi at [n][k], lo at [n][K+k] ====
__global__ __launch_bounds__(256) void wsplit_kernel(
    const float* __restrict__ W, __bf16* __restrict__ B2t, int K, int Nc){
  __shared__ float hi_s[32][33], lo_s[32][33];
  int tx = threadIdx.x & 31, ty = threadIdx.x >> 5;   // 32 x 8
  int k0 = blockIdx.x * 32, n0 = blockIdx.y * 32;
#pragma unroll
  for (int i = 0; i < 4; i++){
    int r = ty + i*8;
    float v = W[(size_t)(k0 + r)*Nc + n0 + tx];
    float h = (float)(__bf16)v;
    hi_s[r][tx] = h;
    lo_s[r][tx] = v - h;
  }
  __syncthreads();
  int K2 = 2*K;
#pragma unroll
  for (int i = 0; i < 4; i++){
    int n = ty + i*8;
    B2t[(size_t)(n0 + n)*K2 + k0 + tx]     = (__bf16)hi_s[tx][n];
    B2t[(size_t)(n0 + n)*K2 + K + k0 + tx] = (__bf16)lo_s[tx][n];
  }
}

// ===== x [N][128] fp32 -> X2 [N][256] bf16 (hi cols 0..127, lo 128..255) ====
__global__ __launch_bounds__(256) void split_kernel(
    const float* __restrict__ X, __bf16* __restrict__ X2, int total){
  int i = (blockIdx.x*256 + threadIdx.x)*4;
  if (i < total){
    int n = i >> 7, c = i & 127;
    float4 v = *(const float4*)(X + i);
    float f[4] = {v.x, v.y, v.z, v.w};
    bf16x4 h, l;
#pragma unroll
    for (int u = 0; u < 4; u++){
      __bf16 hh = (__bf16)f[u];
      h[u] = hh;
      l[u] = (__bf16)(f[u] - (float)hh);
    }
    *(bf16x4*)(X2 + (size_t)n*256 + c)       = h;
    *(bf16x4*)(X2 + (size_t)n*256 + 128 + c) = l;
  }
}

// ========== bf16 MFMA GEMM over K2=2K (hi|lo fold), bf16 output =============
// m97 structure: 128x128 tile, 256 thr, single LDS buffer, global_load_lds
// width=16, 2 barriers/iter, fragment-major LDS (conflict-free both ways).
__global__ __launch_bounds__(256) void gemm_mfma(
    const __bf16* __restrict__ A2, const __bf16* __restrict__ B2t,
    __bf16* __restrict__ Hb, int M, int Nc, int K2){
  __shared__ uint4 As[1024];   // 16 fb x 64 lanes, 16 KiB
  __shared__ uint4 Bs[1024];   // 16 KiB
  int t = threadIdx.x, w = t >> 6, lane = t & 63;
  int mm = lane & 15, q = lane >> 4;
  int blk = blockIdx.x;
  int bm = (blk >> 2) * 128;          // Nc/128 == 4 always here
  int bn = (blk & 3) * 128;

  const __bf16* gA[4];
  const __bf16* gB[4];
#pragma unroll
  for (int jj = 0; jj < 4; jj++){
    int fb = w*4 + jj;
    int i = fb >> 1, s = fb & 1;
    int rowA = bm + i*16 + mm; rowA = (rowA < M) ? rowA : (M - 1);
    gA[jj] = A2 + (size_t)rowA*K2 + s*32 + q*8;
    int rowB = bn + i*16 + mm;
    gB[jj] = B2t + (size_t)rowB*K2 + s*32 + q*8;
  }

  f32x4 acc[4][4];
#pragma unroll
  for (int i = 0; i < 4; i++)
#pragma unroll
    for (int j = 0; j < 4; j++)
#pragma unroll
      for (int r = 0; r < 4; r++) acc[i][j][r] = 0.f;

  const int niter = K2 >> 6;
  for (int it = 0; it < niter; it++){
    __syncthreads();
#pragma unroll
    for (int jj = 0; jj < 4; jj++){
      int fb = w*4 + jj;
      __builtin_amdgcn_global_load_lds(
          (const gbl_u32*)gA[jj], (lds_u32*)(As + fb*64), 16, 0, 0);
      __builtin_amdgcn_global_load_lds(
          (const gbl_u32*)gB[jj], (lds_u32*)(Bs + fb*64), 16, 0, 0);
      gA[jj] += 64;
      gB[jj] += 64;
    }
    __syncthreads();
#pragma unroll
    for (int s = 0; s < 2; s++){
      bf16x8 af[4], bfr[4];
#pragma unroll
      for (int i2 = 0; i2 < 4; i2++){
        int fbA = ((((w & 1)*4) + i2) << 1) | s;
        af[i2]  = *(bf16x8*)&As[fbA*64 + lane];
        int fbB = ((((w >> 1)*4) + i2) << 1) | s;
        bfr[i2] = *(bf16x8*)&Bs[fbB*64 + lane];
      }
#pragma unroll
      for (int i2 = 0; i2 < 4; i2++)
#pragma unroll
        for (int j2 = 0; j2 < 4; j2++)
          acc[i2][j2] = __builtin_amdgcn_mfma_f32_16x16x32_bf16(
              af[i2], bfr[j2], acc[i2][j2], 0, 0, 0);
    }
  }

#pragma unroll
  for (int i2 = 0; i2 < 4; i2++){
    int rbase = bm + ((w & 1)*4 + i2)*16 + q*4;
#pragma unroll
    for (int j2 = 0; j2 < 4; j2++){
      int colc = bn + ((w >> 1)*4 + j2)*16 + mm;
#pragma unroll
      for (int r = 0; r < 4; r++){
        int row = rbase + r;
        if (row < M) Hb[(size_t)row*512 + colc] = (__bf16)acc[i2][j2][r];
      }
    }
  }
}

// ===== attention coefficients from Hb (bf16): one wave per node =============
// lane owns 8 contiguous channels (bf16x8 = 16 B); head = lane>>4 for H=4.
template<int H>
__global__ __launch_bounds__(256) void attn_bf16(
    const __bf16* __restrict__ Hb, const float* __restrict__ asrc,
    const float* __restrict__ adst, float* __restrict__ al_s,
    float* __restrict__ al_d, int N){
  int lane = threadIdx.x & 63, wv = threadIdx.x >> 6;
  int n = blockIdx.x*4 + wv;
  if (n >= N) return;
  float asv[8], adv[8];
#pragma unroll
  for (int u = 0; u < 8; u++){
    asv[u] = asrc[lane*8 + u];
    adv[u] = adst[lane*8 + u];
  }
  bf16x8 v = *(const bf16x8*)(Hb + (size_t)n*512 + lane*8);
  float ss = 0.f, sd = 0.f;
#pragma unroll
  for (int u = 0; u < 8; u++){
    float f = (float)v[u];
    ss += f * asv[u];
    sd += f * adv[u];
  }
  const int red = (H == 4) ? 16 : 64;    // lanes per head group
#pragma unroll
  for (int off = 1; off < 64; off <<= 1){
    if (off < red){
      ss += __shfl_xor(ss, off);
      sd += __shfl_xor(sd, off);
    }
  }
  if ((lane & (red - 1)) == 0){
    int h = (H == 4) ? (lane >> 4) : 0;
    al_s[(size_t)n*H + h] = ss;
    al_d[(size_t)n*H + h] = sd;
  }
}

// ====== channel-sliced gather with FUSED per-head softmax, XCD-pinned =======
// grid g: x = g&7 -> XCD; slice s = x>>1 (128 ch), half = x&1.
// per-slice working set N*256B = 2.56 MB fits one XCD's 4 MB L2.
// Each slice-block needs only head hh = s (H=4) or 0 (H=1), so it recomputes
// that head's segment softmax locally: pass1 shuffle-max, pass2 exp into LDS
// fused with staging (+running sum), normalize by shuffle-reduced sum.
// Deletes alpha_kernel + alphaE/denom traffic (R11 change).
// MODE 0: fp32 out, no ReLU.  MODE 1: ReLU + bf16 hi/lo into feat2 row.
template<int H, int MODE>
__global__ __launch_bounds__(64) void aggregate_slice(
    const __bf16* __restrict__ Hb, const float* __restrict__ al_s,
    const float* __restrict__ al_d, const int* __restrict__ rowptr,
    const int* __restrict__ col, const float* __restrict__ bias,
    float* __restrict__ outF, __bf16* __restrict__ fhi,
    __bf16* __restrict__ flo, int fstride, int nidx, int N){
  int g = blockIdx.x;
  int x = g & 7, idx = g >> 3;
  int s = x >> 1, half = x & 1;
  int d = half * nidx + idx;
  if (d >= N) return;
  int lane = threadIdx.x;
  int start = rowptr[d], end = rowptr[d + 1];
  const int hh = (H == 1) ? 0 : s;
  const float ald = al_d[(size_t)d*H + hh];
  const bf16x2* __restrict__ Hb2 = (const bf16x2*)Hb;   // row = 256 units
  const size_t coff = s*64 + lane;

  // ---- pass 1: per-head max of leaky(al_s[src] + al_d[d]) ----
  float mx = -1e30f;
  for (int e = start + lane; e < end; e += 64){
    int sc = col[e];
    float v = al_s[(size_t)sc*H + hh] + ald;
    v = (v > 0.f) ? v : NSLOPE * v;
    mx = fmaxf(mx, v);
  }
#pragma unroll
  for (int off = 32; off > 0; off >>= 1)
    mx = fmaxf(mx, __shfl_xor(mx, off));

  __shared__ int   src_s[64];
  __shared__ float a_s[64];

  float ax0=0.f, ay0=0.f, ax1=0.f, ay1=0.f;
  float ax2=0.f, ay2=0.f, ax3=0.f, ay3=0.f;
  float lsum = 0.f;

  for (int c0 = start; c0 < end; c0 += 64){
    int cnt = min(64, end - c0);
    if (lane < cnt){
      int e = c0 + lane;
      int sc = col[e];
      float v = al_s[(size_t)sc*H + hh] + ald;
      v = (v > 0.f) ? v : NSLOPE * v;
      float ev = __expf(v - mx);
      src_s[lane] = sc;
      a_s[lane]   = ev;
      lsum += ev;
    }
    __syncthreads();
    int i = 0;
    for (; i + 4 <= cnt; i += 4){
      int s0 = src_s[i],   s1 = src_s[i+1];
      int s2 = src_s[i+2], s3 = src_s[i+3];
      float e0 = a_s[i],   e1 = a_s[i+1];
      float e2 = a_s[i+2], e3 = a_s[i+3];
      bf16x2 v0 = Hb2[(size_t)s0*256 + coff];
      bf16x2 v1 = Hb2[(size_t)s1*256 + coff];
      bf16x2 v2 = Hb2[(size_t)s2*256 + coff];
      bf16x2 v3 = Hb2[(size_t)s3*256 + coff];
      ax0 += e0*(float)v0[0]; ay0 += e0*(float)v0[1];
      ax1 += e1*(float)v1[0]; ay1 += e1*(float)v1[1];
      ax2 += e2*(float)v2[0]; ay2 += e2*(float)v2[1];
      ax3 += e3*(float)v3[0]; ay3 += e3*(float)v3[1];
    }
    for (; i < cnt; i++){
      int s0 = src_s[i];
      float e0 = a_s[i];
      bf16x2 v0 = Hb2[(size_t)s0*256 + coff];
      ax0 += e0*(float)v0[0]; ay0 += e0*(float)v0[1];
    }
    __syncthreads();
  }

  // denom = sum of e over all edges (each edge staged by exactly one lane)
#pragma unroll
  for (int off = 32; off > 0; off >>= 1)
    lsum += __shfl_xor(lsum, off);

  float accx = (ax0 + ax1) + (ax2 + ax3);
  float accy = (ay0 + ay1) + (ay2 + ay3);
  float invd = 1.f / lsum;
  int c = s*128 + lane*2;
  float2 bv = *(const float2*)(bias + c);
  float r0 = accx * invd + bv.x;
  float r1 = accy * invd + bv.y;
  if (MODE == 1){
    r0 = fmaxf(r0, 0.f); r1 = fmaxf(r1, 0.f);
    __bf16 h0 = (__bf16)r0, h1 = (__bf16)r1;
    bf16x2 hv; hv[0] = h0; hv[1] = h1;
    bf16x2 lv; lv[0] = (__bf16)(r0 - (float)h0); lv[1] = (__bf16)(r1 - (float)h1);
    *(bf16x2*)(fhi + (size_t)d*fstride + c) = hv;
    *(bf16x2*)(flo + (size_t)d*fstride + c) = lv;
  } else {
    *(float2*)(outF + (size_t)d*512 + c) = make_float2(r0, r1);
  }
}

// =========================== launch =========================================
extern "C" void kernel_launch(void* const* d_in, const int* in_sizes, int n_in,
                              void* d_out, int out_size, void* d_ws, size_t ws_size,
                              hipStream_t stream){
  const float* x   = (const float*)d_in[0];
  const int*   ei  = (const int*)  d_in[1];
  const float* W1  = (const float*)d_in[2];
  const float* as1 = (const float*)d_in[3];
  const float* ad1 = (const float*)d_in[4];
  const float* b1  = (const float*)d_in[5];
  const float* W2  = (const float*)d_in[6];
  const float* as2 = (const float*)d_in[7];
  const float* ad2 = (const float*)d_in[8];
  const float* b2  = (const float*)d_in[9];
  const float* W3  = (const float*)d_in[10];
  const float* as3 = (const float*)d_in[11];
  const float* ad3 = (const float*)d_in[12];
  const float* b3  = (const float*)d_in[13];
  float* out = (float*)d_out;

  const int N = in_sizes[0] / 128;   // 10000
  const int E = in_sizes[1] / 2;     // 320000
  const int F = 512;
  const int Etot = E + N;
  const int nidx = (N + 1) / 2;

  // workspace carve-up
  __bf16* feat2  = (__bf16*)d_ws;                     // N*1024 bf16 (hi|lo)
  float*  al_s   = (float*)(feat2 + (size_t)N*1024);  // N*4
  float*  al_d   = al_s + (size_t)N*4;                // N*4
  __bf16* X2     = (__bf16*)(al_d + (size_t)N*4);     // N*256 bf16 (layer-1 A)
  int*    cnt    = (int*)(X2 + (size_t)N*256);        // N
  int*    rowptr = cnt + N;                           // N+1
  int*    cursor = rowptr + N + 1;                    // N
  int*    col    = cursor + N;                        // E+N
  uintptr_t p  = (uintptr_t)(col + Etot);
  p = (p + 15) & ~(uintptr_t)15;
  __bf16* B2t = (__bf16*)p;                           // 512*1024 bf16
  __bf16* Hb  = B2t + 512*1024;                       // N*512 bf16 (gather)

  // CSR by destination
  init_cnt_kernel<<<(N+255)/256, 256, 0, stream>>>(cnt, N);
  hist_kernel<<<(E+255)/256, 256, 0, stream>>>(ei, E, cnt);
  scan_kernel<<<1, 1024, 0, stream>>>(cnt, rowptr, cursor, N);
  fill_kernel<<<(E+N+255)/256, 256, 0, stream>>>(ei, E, N, cursor, col);

  const int ggrid = ((N + 127)/128) * (F/128);   // 79 * 4 = 316 blocks
  const int agrid = nidx * 8;
  const int ngrid = (N + 3)/4;

  // ---- layer 1: x[N,128] @ W1[128,512]  (K2 = 256) ----
  split_kernel<<<(N*128/4 + 255)/256, 256, 0, stream>>>(x, X2, N*128);
  wsplit_kernel<<<dim3(128/32, F/32), 256, 0, stream>>>(W1, B2t, 128, F);
  gemm_mfma<<<ggrid, 256, 0, stream>>>(X2, B2t, Hb, N, F, 256);
  attn_bf16<4><<<ngrid, 256, 0, stream>>>(Hb, as1, ad1, al_s, al_d, N);
  aggregate_slice<4,1><<<agrid, 64, 0, stream>>>(Hb, al_s, al_d, rowptr, col, b1,
      (float*)nullptr, feat2, feat2 + 512, 1024, nidx, N);

  // ---- layer 2: feat[N,512] @ W2[512,512]  (K2 = 1024) ----
  wsplit_kernel<<<dim3(F/32, F/32), 256, 0, stream>>>(W2, B2t, F, F);
  gemm_mfma<<<ggrid, 256, 0, stream>>>(feat2, B2t, Hb, N, F, 1024);
  attn_bf16<4><<<ngrid, 256, 0, stream>>>(Hb, as2, ad2, al_s, al_d, N);
  aggregate_slice<4,1><<<agrid, 64, 0, stream>>>(Hb, al_s, al_d, rowptr, col, b2,
      (float*)nullptr, feat2, feat2 + 512, 1024, nidx, N);

  // ---- layer 3: feat[N,512] @ W3[512,512], heads=1  (K2 = 1024) ----
  wsplit_kernel<<<dim3(F/32, F/32), 256, 0, stream>>>(W3, B2t, F, F);
  gemm_mfma<<<ggrid, 256, 0, stream>>>(feat2, B2t, Hb, N, F, 1024);
  attn_bf16<1><<<ngrid, 256, 0, stream>>>(Hb, as3, ad3, al_s, al_d, N);
  aggregate_slice<1,0><<<agrid, 64, 0, stream>>>(Hb, al_s, al_d, rowptr, col, b3,
      out, (__bf16*)nullptr, (__bf16*)nullptr, 0, nidx, N);
}

// Round 13
// 351.800 us; speedup vs baseline: 1.2410x; 1.0184x over previous
//
#include <hip/hip_runtime.h>

#define NSLOPE 0.2f

typedef __bf16 bf16x8 __attribute__((ext_vector_type(8)));
typedef __bf16 bf16x4 __attribute__((ext_vector_type(4)));
typedef __bf16 bf16x2 __attribute__((ext_vector_type(2)));
typedef float  f32x4  __attribute__((ext_vector_type(4)));

typedef uint32_t __attribute__((address_space(1))) gbl_u32;
typedef uint32_t __attribute__((address_space(3))) lds_u32;

// ======================= CSR build (per-launch; ws is re-poisoned) ==========
__global__ void hist_kernel(const int* __restrict__ ei, int E, int* cnt){
  int e = blockIdx.x*blockDim.x + threadIdx.x;
  if (e < E) atomicAdd(&cnt[ei[E + e]], 1);    // dst row of edge_index
}

// single-block scan, wave-shuffle based
__global__ void scan_kernel(const int* __restrict__ cnt, int* __restrict__ rowptr,
                            int* __restrict__ cursor, int n){
  __shared__ int wsum[16];
  __shared__ int carry, chunk_total;
  int t = threadIdx.x, lane = t & 63, wid = t >> 6;
  if (t == 0) carry = 0;
  __syncthreads();
  for (int base = 0; base < n; base += 1024){
    int idx = base + t;
    int v = (idx < n) ? cnt[idx] : 0;
    int inc = v;
#pragma unroll
    for (int off = 1; off < 64; off <<= 1){
      int u = __shfl_up(inc, off);
      if (lane >= off) inc += u;
    }
    if (lane == 63) wsum[wid] = inc;
    __syncthreads();
    if (t == 0){
      int s = 0;
#pragma unroll
      for (int i = 0; i < 16; i++){ int x = wsum[i]; wsum[i] = s; s += x; }
      chunk_total = s;
    }
    __syncthreads();
    int excl = carry + wsum[wid] + inc - v;
    if (idx < n){ rowptr[idx] = excl; cursor[idx] = excl; }
    __syncthreads();
    if (t == 0) carry += chunk_total;
    __syncthreads();
  }
  if (t == 0) rowptr[n] = carry;
}

__global__ void fill_kernel(const int* __restrict__ ei, int E, int n,
                            int* cursor, int* __restrict__ col){
  int i = blockIdx.x*blockDim.x + threadIdx.x;
  if (i < E){
    int s = ei[i], d = ei[E + i];
    int slot = atomicAdd(&cursor[d], 1);
    col[slot] = s;
  } else if (i < E + n){
    int v = i - E;                             // self loop (v -> v)
    int slot = atomicAdd(&cursor[v], 1);
    col[slot] = v;
  }
}

// ===== W [K][Nc] fp32 -> Bt [Nc][2K] bf16 split body (hi @ k, lo @ K+k) ====
__device__ __forceinline__ void wsplit_body(
    const float* __restrict__ W, __bf16* __restrict__ Bt, int K, int Nc,
    int kb, int nb, float (*hi_s)[33], float (*lo_s)[33]){
  int tx = threadIdx.x & 31, ty = threadIdx.x >> 5;   // 32 x 8
  int k0 = kb * 32, n0 = nb * 32;
#pragma unroll
  for (int i = 0; i < 4; i++){
    int r = ty + i*8;
    float v = W[(size_t)(k0 + r)*Nc + n0 + tx];
    float h = (float)(__bf16)v;
    hi_s[r][tx] = h;
    lo_s[r][tx] = v - h;
  }
  __syncthreads();
  int K2 = 2*K;
#pragma unroll
  for (int i = 0; i < 4; i++){
    int n = ty + i*8;
    Bt[(size_t)(n0 + n)*K2 + k0 + tx]     = (__bf16)hi_s[tx][n];
    Bt[(size_t)(n0 + n)*K2 + K + k0 + tx] = (__bf16)lo_s[tx][n];
  }
}

// ===== fused prep: cnt init + split(x)->X2 + wsplit(W1,W2,W3) ==============
// sections by blockIdx: [0,1250) split x; [1250,1314) W1; then 256 + 256.
__global__ __launch_bounds__(256) void prep_kernel(
    const float* __restrict__ x, __bf16* __restrict__ X2,
    const float* __restrict__ W1, __bf16* __restrict__ B1t,
    const float* __restrict__ W2, __bf16* __restrict__ B2t,
    const float* __restrict__ W3, __bf16* __restrict__ B3t,
    int* __restrict__ cnt, int N){
  __shared__ float hi_s[32][33], lo_s[32][33];
  int b = blockIdx.x, t = threadIdx.x;
  int gid = b*256 + t;
  if (gid < N) cnt[gid] = 1;                 // self-loop pre-count
  const int nb_split = (N*32 + 255) / 256;   // N*128/4 elems / 256 thr = 1250
  if (b < nb_split){
    int i = gid * 4;
    if (i < N*128){
      int n = i >> 7, c = i & 127;
      float4 v = *(const float4*)(x + i);
      float f[4] = {v.x, v.y, v.z, v.w};
      bf16x4 h, l;
#pragma unroll
      for (int u = 0; u < 4; u++){
        __bf16 hh = (__bf16)f[u];
        h[u] = hh;
        l[u] = (__bf16)(f[u] - (float)hh);
      }
      *(bf16x4*)(X2 + (size_t)n*256 + c)       = h;
      *(bf16x4*)(X2 + (size_t)n*256 + 128 + c) = l;
    }
  } else if (b < nb_split + 64){
    int bb = b - nb_split;                   // W1: K=128 -> 4 x 16
    wsplit_body(W1, B1t, 128, 512, bb & 3, bb >> 2, hi_s, lo_s);
  } else if (b < nb_split + 64 + 256){
    int bb = b - nb_split - 64;              // W2: 16 x 16
    wsplit_body(W2, B2t, 512, 512, bb & 15, bb >> 4, hi_s, lo_s);
  } else {
    int bb = b - nb_split - 320;             // W3: 16 x 16
    wsplit_body(W3, B3t, 512, 512, bb & 15, bb >> 4, hi_s, lo_s);
  }
}

// ========== bf16 MFMA GEMM over K2=2K (hi|lo fold), bf16 output =============
// m97 structure: 128x128 tile, 256 thr, single LDS buffer, global_load_lds
// width=16, 2 barriers/iter, fragment-major LDS (conflict-free both ways).
__global__ __launch_bounds__(256) void gemm_mfma(
    const __bf16* __restrict__ A2, const __bf16* __restrict__ B2t,
    __bf16* __restrict__ Hb, int M, int Nc, int K2){
  __shared__ uint4 As[1024];   // 16 fb x 64 lanes, 16 KiB
  __shared__ uint4 Bs[1024];   // 16 KiB
  int t = threadIdx.x, w = t >> 6, lane = t & 63;
  int mm = lane & 15, q = lane >> 4;
  int blk = blockIdx.x;
  int bm = (blk >> 2) * 128;          // Nc/128 == 4 always here
  int bn = (blk & 3) * 128;

  const __bf16* gA[4];
  const __bf16* gB[4];
#pragma unroll
  for (int jj = 0; jj < 4; jj++){
    int fb = w*4 + jj;
    int i = fb >> 1, s = fb & 1;
    int rowA = bm + i*16 + mm; rowA = (rowA < M) ? rowA : (M - 1);
    gA[jj] = A2 + (size_t)rowA*K2 + s*32 + q*8;
    int rowB = bn + i*16 + mm;
    gB[jj] = B2t + (size_t)rowB*K2 + s*32 + q*8;
  }

  f32x4 acc[4][4];
#pragma unroll
  for (int i = 0; i < 4; i++)
#pragma unroll
    for (int j = 0; j < 4; j++)
#pragma unroll
      for (int r = 0; r < 4; r++) acc[i][j][r] = 0.f;

  const int niter = K2 >> 6;
  for (int it = 0; it < niter; it++){
    __syncthreads();
#pragma unroll
    for (int jj = 0; jj < 4; jj++){
      int fb = w*4 + jj;
      __builtin_amdgcn_global_load_lds(
          (const gbl_u32*)gA[jj], (lds_u32*)(As + fb*64), 16, 0, 0);
      __builtin_amdgcn_global_load_lds(
          (const gbl_u32*)gB[jj], (lds_u32*)(Bs + fb*64), 16, 0, 0);
      gA[jj] += 64;
      gB[jj] += 64;
    }
    __syncthreads();
#pragma unroll
    for (int s = 0; s < 2; s++){
      bf16x8 af[4], bfr[4];
#pragma unroll
      for (int i2 = 0; i2 < 4; i2++){
        int fbA = ((((w & 1)*4) + i2) << 1) | s;
        af[i2]  = *(bf16x8*)&As[fbA*64 + lane];
        int fbB = ((((w >> 1)*4) + i2) << 1) | s;
        bfr[i2] = *(bf16x8*)&Bs[fbB*64 + lane];
      }
#pragma unroll
      for (int i2 = 0; i2 < 4; i2++)
#pragma unroll
        for (int j2 = 0; j2 < 4; j2++)
          acc[i2][j2] = __builtin_amdgcn_mfma_f32_16x16x32_bf16(
              af[i2], bfr[j2], acc[i2][j2], 0, 0, 0);
    }
  }

#pragma unroll
  for (int i2 = 0; i2 < 4; i2++){
    int rbase = bm + ((w & 1)*4 + i2)*16 + q*4;
#pragma unroll
    for (int j2 = 0; j2 < 4; j2++){
      int colc = bn + ((w >> 1)*4 + j2)*16 + mm;
#pragma unroll
      for (int r = 0; r < 4; r++){
        int row = rbase + r;
        if (row < M) Hb[(size_t)row*512 + colc] = (__bf16)acc[i2][j2][r];
      }
    }
  }
}

// ===== attention coefficients from Hb (bf16): one wave per node =============
template<int H>
__global__ __launch_bounds__(256) void attn_bf16(
    const __bf16* __restrict__ Hb, const float* __restrict__ asrc,
    const float* __restrict__ adst, float* __restrict__ al_s,
    float* __restrict__ al_d, int N){
  int lane = threadIdx.x & 63, wv = threadIdx.x >> 6;
  int n = blockIdx.x*4 + wv;
  if (n >= N) return;
  float asv[8], adv[8];
#pragma unroll
  for (int u = 0; u < 8; u++){
    asv[u] = asrc[lane*8 + u];
    adv[u] = adst[lane*8 + u];
  }
  bf16x8 v = *(const bf16x8*)(Hb + (size_t)n*512 + lane*8);
  float ss = 0.f, sd = 0.f;
#pragma unroll
  for (int u = 0; u < 8; u++){
    float f = (float)v[u];
    ss += f * asv[u];
    sd += f * adv[u];
  }
  const int red = (H == 4) ? 16 : 64;    // lanes per head group
#pragma unroll
  for (int off = 1; off < 64; off <<= 1){
    if (off < red){
      ss += __shfl_xor(ss, off);
      sd += __shfl_xor(sd, off);
    }
  }
  if ((lane & (red - 1)) == 0){
    int h = (H == 4) ? (lane >> 4) : 0;
    al_s[(size_t)n*H + h] = ss;
    al_d[(size_t)n*H + h] = sd;
  }
}

// ====== channel-sliced gather with FUSED per-head softmax, XCD-pinned =======
template<int H, int MODE>
__global__ __launch_bounds__(64) void aggregate_slice(
    const __bf16* __restrict__ Hb, const float* __restrict__ al_s,
    const float* __restrict__ al_d, const int* __restrict__ rowptr,
    const int* __restrict__ col, const float* __restrict__ bias,
    float* __restrict__ outF, __bf16* __restrict__ fhi,
    __bf16* __restrict__ flo, int fstride, int nidx, int N){
  int g = blockIdx.x;
  int x = g & 7, idx = g >> 3;
  int s = x >> 1, half = x & 1;
  int d = half * nidx + idx;
  if (d >= N) return;
  int lane = threadIdx.x;
  int start = rowptr[d], end = rowptr[d + 1];
  const int hh = (H == 1) ? 0 : s;
  const float ald = al_d[(size_t)d*H + hh];
  const bf16x2* __restrict__ Hb2 = (const bf16x2*)Hb;   // row = 256 units
  const size_t coff = s*64 + lane;

  float mx = -1e30f;
  for (int e = start + lane; e < end; e += 64){
    int sc = col[e];
    float v = al_s[(size_t)sc*H + hh] + ald;
    v = (v > 0.f) ? v : NSLOPE * v;
    mx = fmaxf(mx, v);
  }
#pragma unroll
  for (int off = 32; off > 0; off >>= 1)
    mx = fmaxf(mx, __shfl_xor(mx, off));

  __shared__ int   src_s[64];
  __shared__ float a_s[64];

  float ax0=0.f, ay0=0.f, ax1=0.f, ay1=0.f;
  float ax2=0.f, ay2=0.f, ax3=0.f, ay3=0.f;
  float lsum = 0.f;

  for (int c0 = start; c0 < end; c0 += 64){
    int cnt = min(64, end - c0);
    if (lane < cnt){
      int e = c0 + lane;
      int sc = col[e];
      float v = al_s[(size_t)sc*H + hh] + ald;
      v = (v > 0.f) ? v : NSLOPE * v;
      float ev = __expf(v - mx);
      src_s[lane] = sc;
      a_s[lane]   = ev;
      lsum += ev;
    }
    __syncthreads();
    int i = 0;
    for (; i + 4 <= cnt; i += 4){
      int s0 = src_s[i],   s1 = src_s[i+1];
      int s2 = src_s[i+2], s3 = src_s[i+3];
      float e0 = a_s[i],   e1 = a_s[i+1];
      float e2 = a_s[i+2], e3 = a_s[i+3];
      bf16x2 v0 = Hb2[(size_t)s0*256 + coff];
      bf16x2 v1 = Hb2[(size_t)s1*256 + coff];
      bf16x2 v2 = Hb2[(size_t)s2*256 + coff];
      bf16x2 v3 = Hb2[(size_t)s3*256 + coff];
      ax0 += e0*(float)v0[0]; ay0 += e0*(float)v0[1];
      ax1 += e1*(float)v1[0]; ay1 += e1*(float)v1[1];
      ax2 += e2*(float)v2[0]; ay2 += e2*(float)v2[1];
      ax3 += e3*(float)v3[0]; ay3 += e3*(float)v3[1];
    }
    for (; i < cnt; i++){
      int s0 = src_s[i];
      float e0 = a_s[i];
      bf16x2 v0 = Hb2[(size_t)s0*256 + coff];
      ax0 += e0*(float)v0[0]; ay0 += e0*(float)v0[1];
    }
    __syncthreads();
  }

#pragma unroll
  for (int off = 32; off > 0; off >>= 1)
    lsum += __shfl_xor(lsum, off);

  float accx = (ax0 + ax1) + (ax2 + ax3);
  float accy = (ay0 + ay1) + (ay2 + ay3);
  float invd = 1.f / lsum;
  int c = s*128 + lane*2;
  float2 bv = *(const float2*)(bias + c);
  float r0 = accx * invd + bv.x;
  float r1 = accy * invd + bv.y;
  if (MODE == 1){
    r0 = fmaxf(r0, 0.f); r1 = fmaxf(r1, 0.f);
    __bf16 h0 = (__bf16)r0, h1 = (__bf16)r1;
    bf16x2 hv; hv[0] = h0; hv[1] = h1;
    bf16x2 lv; lv[0] = (__bf16)(r0 - (float)h0); lv[1] = (__bf16)(r1 - (float)h1);
    *(bf16x2*)(fhi + (size_t)d*fstride + c) = hv;
    *(bf16x2*)(flo + (size_t)d*fstride + c) = lv;
  } else {
    *(float2*)(outF + (size_t)d*512 + c) = make_float2(r0, r1);
  }
}

// =========================== launch =========================================
extern "C" void kernel_launch(void* const* d_in, const int* in_sizes, int n_in,
                              void* d_out, int out_size, void* d_ws, size_t ws_size,
                              hipStream_t stream){
  const float* x   = (const float*)d_in[0];
  const int*   ei  = (const int*)  d_in[1];
  const float* W1  = (const float*)d_in[2];
  const float* as1 = (const float*)d_in[3];
  const float* ad1 = (const float*)d_in[4];
  const float* b1  = (const float*)d_in[5];
  const float* W2  = (const float*)d_in[6];
  const float* as2 = (const float*)d_in[7];
  const float* ad2 = (const float*)d_in[8];
  const float* b2  = (const float*)d_in[9];
  const float* W3  = (const float*)d_in[10];
  const float* as3 = (const float*)d_in[11];
  const float* ad3 = (const float*)d_in[12];
  const float* b3  = (const float*)d_in[13];
  float* out = (float*)d_out;

  const int N = in_sizes[0] / 128;   // 10000
  const int E = in_sizes[1] / 2;     // 320000
  const int F = 512;
  const int Etot = E + N;
  const int nidx = (N + 1) / 2;

  // workspace carve-up
  __bf16* feat2  = (__bf16*)d_ws;                     // N*1024 bf16 (hi|lo)
  float*  al_s   = (float*)(feat2 + (size_t)N*1024);  // N*4
  float*  al_d   = al_s + (size_t)N*4;                // N*4
  __bf16* X2     = (__bf16*)(al_d + (size_t)N*4);     // N*256 bf16 (layer-1 A)
  int*    cnt    = (int*)(X2 + (size_t)N*256);        // N
  int*    rowptr = cnt + N;                           // N+1
  int*    cursor = rowptr + N + 1;                    // N
  int*    col    = cursor + N;                        // E+N
  uintptr_t p  = (uintptr_t)(col + Etot);
  p = (p + 15) & ~(uintptr_t)15;
  __bf16* B1t = (__bf16*)p;                           // 512*256 bf16
  __bf16* B2t = B1t + 512*256;                        // 512*1024 bf16
  __bf16* B3t = B2t + 512*1024;                       // 512*1024 bf16
  __bf16* Hb  = B3t + 512*1024;                       // N*512 bf16 (gather)

  const int nb_split = (N*32 + 255)/256;              // 1250
  const int pgrid = nb_split + 64 + 256 + 256;        // 1826

  // prep: cnt=1, split x, split W1/W2/W3 (one dispatch, off critical path mid-pipe)
  prep_kernel<<<pgrid, 256, 0, stream>>>(x, X2, W1, B1t, W2, B2t, W3, B3t, cnt, N);
  hist_kernel<<<(E+255)/256, 256, 0, stream>>>(ei, E, cnt);
  scan_kernel<<<1, 1024, 0, stream>>>(cnt, rowptr, cursor, N);
  fill_kernel<<<(E+N+255)/256, 256, 0, stream>>>(ei, E, N, cursor, col);

  const int ggrid = ((N + 127)/128) * (F/128);   // 79 * 4 = 316 blocks
  const int agrid = nidx * 8;
  const int ngrid = (N + 3)/4;

  // ---- layer 1: x[N,128] @ W1[128,512]  (K2 = 256) ----
  gemm_mfma<<<ggrid, 256, 0, stream>>>(X2, B1t, Hb, N, F, 256);
  attn_bf16<4><<<ngrid, 256, 0, stream>>>(Hb, as1, ad1, al_s, al_d, N);
  aggregate_slice<4,1><<<agrid, 64, 0, stream>>>(Hb, al_s, al_d, rowptr, col, b1,
      (float*)nullptr, feat2, feat2 + 512, 1024, nidx, N);

  // ---- layer 2: feat[N,512] @ W2[512,512]  (K2 = 1024) ----
  gemm_mfma<<<ggrid, 256, 0, stream>>>(feat2, B2t, Hb, N, F, 1024);
  attn_bf16<4><<<ngrid, 256, 0, stream>>>(Hb, as2, ad2, al_s, al_d, N);
  aggregate_slice<4,1><<<agrid, 64, 0, stream>>>(Hb, al_s, al_d, rowptr, col, b2,
      (float*)nullptr, feat2, feat2 + 512, 1024, nidx, N);

  // ---- layer 3: feat[N,512] @ W3[512,512], heads=1  (K2 = 1024) ----
  gemm_mfma<<<ggrid, 256, 0, stream>>>(feat2, B3t, Hb, N, F, 1024);
  attn_bf16<1><<<ngrid, 256, 0, stream>>>(Hb, as3, ad3, al_s, al_d, N);
  aggregate_slice<1,0><<<agrid, 64, 0, stream>>>(Hb, al_s, al_d, rowptr, col, b3,
      out, (__bf16*)nullptr, (__bf16*)nullptr, 0, nidx, N);
}